// Round 10
// baseline (361.380 us; speedup 1.0000x reference)
//
#include <hip/hip_runtime.h>

// Problem constants
#define HD    16
#define DH    128
#define BB    2
#define SS    2048
#define DM    2048
#define NQKV  6144   // 3*HD*DH
#define MTOT  4096   // BB*SS

typedef short   bfx8  __attribute__((ext_vector_type(8)));   // 8 bf16 (4 VGPRs)
typedef float   f32x4 __attribute__((ext_vector_type(4)));

__device__ __forceinline__ unsigned short f2bf(float f) {
  union { float f; unsigned int u; } c; c.f = f;
  unsigned int u = c.u + 0x7FFFu + ((c.u >> 16) & 1u);
  return (unsigned short)(u >> 16);
}

__device__ __forceinline__ void gload_lds16(const unsigned short* g, unsigned short* l) {
  __builtin_amdgcn_global_load_lds(
      (const __attribute__((address_space(1))) unsigned int*)g,
      (__attribute__((address_space(3))) unsigned int*)l, 16, 0, 0);
}

// raw barrier fenced against compiler reordering (no vmcnt/lgkmcnt drain)
#define BARS() do { __builtin_amdgcn_sched_barrier(0); __builtin_amdgcn_s_barrier(); \
                    __builtin_amdgcn_sched_barrier(0); } while (0)
#define VMCNT2() do { asm volatile("s_waitcnt vmcnt(2)" ::: "memory"); \
                      __builtin_amdgcn_sched_barrier(0); } while (0)

// ---------------- f32 -> bf16 cast ----------------
__global__ __launch_bounds__(256) void f32_to_bf16_k(const float* __restrict__ in,
                                                     unsigned short* __restrict__ out, int n4) {
  int i = (blockIdx.x * 256 + threadIdx.x);
  if (i >= n4) return;
  const float4 v = *(const float4*)(in + (size_t)i * 4);
  ushort4 o;
  o.x = f2bf(v.x); o.y = f2bf(v.y); o.z = f2bf(v.z); o.w = f2bf(v.w);
  *(ushort4*)(out + (size_t)i * 4) = o;
}

// ---------------- f32 [R][C] -> bf16 [C][R] transpose ----------------
__global__ __launch_bounds__(256) void transpose_f32_bf16_k(const float* __restrict__ in,
                                                            unsigned short* __restrict__ out,
                                                            int R, int C) {
  __shared__ float t[32][33];
  const int c0 = blockIdx.x * 32, r0 = blockIdx.y * 32;
  const int tx = threadIdx.x & 31, ty = threadIdx.x >> 5;  // 32 x 8
#pragma unroll
  for (int i = 0; i < 4; i++) {
    int r = r0 + ty + i * 8;
    t[ty + i * 8][tx] = in[(size_t)r * C + c0 + tx];
  }
  __syncthreads();
#pragma unroll
  for (int i = 0; i < 4; i++) {
    int c = c0 + ty + i * 8;
    out[(size_t)c * R + r0 + tx] = f2bf(t[tx][ty + i * 8]);
  }
}

// ---------------- 256x256 8-phase bf16 GEMM for QKV: C = A[M][K] * Bt[N][K]^T ----------------
// 8 waves (2M x 4N), BK=64, double-buffered swizzled LDS (128 KB), per-quadrant
// barrier interleave, counted vmcnt(2) once per K-tile, setprio around MFMA.
// Split epilogue -> Qg/Kg [b][h][s][d], Vg [b][h][d][s].
__global__ __launch_bounds__(512, 2) void gemm256_qkv_k(const unsigned short* __restrict__ A,
                                                        const unsigned short* __restrict__ Bt,
                                                        unsigned short* __restrict__ Qg,
                                                        unsigned short* __restrict__ Kg,
                                                        unsigned short* __restrict__ Vg,
                                                        int K) {
  __shared__ __align__(16) unsigned short Asb[2][256 * 64];  // 64 KB
  __shared__ __align__(16) unsigned short Bsb[2][256 * 64];  // 64 KB
  const int tid = threadIdx.x;
  const int lane = tid & 63, wid = tid >> 6;
  const int wr = wid >> 2, wc = wid & 3;            // 2 x 4 wave grid
  const int cbase = lane & 15, rgrp = lane >> 4;
  const int bid = (int)blockIdx.x;
  const int id = (bid & 7) * 48 + (bid >> 3);       // XCD-bijective (384 = 8*48)
  const int nb = id >> 4, mb = id & 15;             // XCD owns 3 n-panels (B L2-resident)
  const size_t m0 = (size_t)mb * 256, n0 = (size_t)nb * 256;
  const int nkt = K >> 6;                           // 32 K-tiles of 64

  // half: 0=A rows 0-127, 1=A rows 128-255, 2=B rows 0-127, 3=B rows 128-255.
  // dest buffer slot = (u)&1; src K-tile clamped (harmless overstage of last tile).
#define STAGE_HALF(u_, half_) do {                                                      \
    const int uc_ = ((u_) < nkt ? (u_) : (nkt - 1));                                    \
    unsigned short* ldsb_ = (((half_) < 2) ? &Asb[(u_) & 1][0] : &Bsb[(u_) & 1][0])     \
                            + ((half_) & 1) * (128 * 64);                               \
    const unsigned short* gb_ = (((half_) < 2)                                          \
        ? A  + (m0 + (size_t)((half_) & 1) * 128) * (size_t)K                           \
        : Bt + (n0 + (size_t)((half_) & 1) * 128) * (size_t)K);                         \
    _Pragma("unroll")                                                                   \
    for (int ld_ = 0; ld_ < 2; ld_++) {                                                 \
      const int idx_ = ld_ * 512 + tid;                                                 \
      const int row_ = idx_ >> 3, seg_ = idx_ & 7;                                      \
      gload_lds16(gb_ + (size_t)row_ * K + uc_ * 64 +                                   \
                      (((seg_ * 16) ^ ((row_ & 7) << 4)) >> 1),                         \
                  ldsb_ + idx_ * 8);                                                    \
    } } while (0)

  // lane-fixed ds_read elem offsets (swizzled); frag (mf,ks): a_off[ks] + mf*1024
  const int axor = (cbase & 7) << 4;
  int a_off[2], b_off[2];
#pragma unroll
  for (int ks = 0; ks < 2; ks++) {
    a_off[ks] = ((wr * 128 + cbase) * 128 + ((ks * 64 + rgrp * 16) ^ axor)) >> 1;
    b_off[ks] = ((wc * 64 + cbase) * 128 + ((ks * 64 + rgrp * 16) ^ axor)) >> 1;
  }

  f32x4 acc[8][4];
  const f32x4 z = {0.f, 0.f, 0.f, 0.f};
#pragma unroll
  for (int mf = 0; mf < 8; mf++)
#pragma unroll
    for (int nf = 0; nf < 4; nf++) acc[mf][nf] = z;

  // prologue: tile0 all 4 halves + tile1 h0; wait tile0 landed (2 loads in flight)
  STAGE_HALF(0, 0); STAGE_HALF(0, 1); STAGE_HALF(0, 2); STAGE_HALF(0, 3);
  STAGE_HALF(1, 0);
  VMCNT2();
  BARS();

#pragma unroll 1
  for (int u = 0; u < nkt; ++u) {
    const unsigned short* As_ = &Asb[u & 1][0];
    const unsigned short* Bs_ = &Bsb[u & 1][0];
    bfx8 a03[4][2], a47[4][2], b01[2][2], b23[2][2];

    // ---- Q1: issue A(m0-3)+B(n0-1) reads, stage (u+1) A-half1 ----
#pragma unroll
    for (int mf = 0; mf < 4; mf++)
#pragma unroll
      for (int ks = 0; ks < 2; ks++)
        a03[mf][ks] = *(const bfx8*)(As_ + a_off[ks] + mf * 1024);
#pragma unroll
    for (int nf = 0; nf < 2; nf++)
#pragma unroll
      for (int ks = 0; ks < 2; ks++)
        b01[nf][ks] = *(const bfx8*)(Bs_ + b_off[ks] + nf * 1024);
    STAGE_HALF(u + 1, 1);
    BARS();
    __builtin_amdgcn_s_setprio(1);
#pragma unroll
    for (int mf = 0; mf < 4; mf++)
#pragma unroll
      for (int nf = 0; nf < 2; nf++)
#pragma unroll
        for (int ks = 0; ks < 2; ks++)
          acc[mf][nf] = __builtin_amdgcn_mfma_f32_16x16x32_bf16(a03[mf][ks], b01[nf][ks], acc[mf][nf], 0, 0, 0);
    __builtin_amdgcn_s_setprio(0);
    BARS();

    // ---- Q2: issue B(n2-3) reads, stage (u+1) B-half0 ----
#pragma unroll
    for (int nf = 0; nf < 2; nf++)
#pragma unroll
      for (int ks = 0; ks < 2; ks++)
        b23[nf][ks] = *(const bfx8*)(Bs_ + b_off[ks] + (nf + 2) * 1024);
    STAGE_HALF(u + 1, 2);
    BARS();
    __builtin_amdgcn_s_setprio(1);
#pragma unroll
    for (int mf = 0; mf < 4; mf++)
#pragma unroll
      for (int nf = 0; nf < 2; nf++)
#pragma unroll
        for (int ks = 0; ks < 2; ks++)
          acc[mf][nf + 2] = __builtin_amdgcn_mfma_f32_16x16x32_bf16(a03[mf][ks], b23[nf][ks], acc[mf][nf + 2], 0, 0, 0);
    __builtin_amdgcn_s_setprio(0);
    BARS();

    // ---- Q3: issue A(m4-7) reads, stage (u+1) B-half1 ----
#pragma unroll
    for (int mf = 0; mf < 4; mf++)
#pragma unroll
      for (int ks = 0; ks < 2; ks++)
        a47[mf][ks] = *(const bfx8*)(As_ + a_off[ks] + (mf + 4) * 1024);
    STAGE_HALF(u + 1, 3);
    BARS();
    __builtin_amdgcn_s_setprio(1);
#pragma unroll
    for (int mf = 0; mf < 4; mf++)
#pragma unroll
      for (int nf = 0; nf < 2; nf++)
#pragma unroll
        for (int ks = 0; ks < 2; ks++)
          acc[mf + 4][nf] = __builtin_amdgcn_mfma_f32_16x16x32_bf16(a47[mf][ks], b01[nf][ks], acc[mf + 4][nf], 0, 0, 0);
    __builtin_amdgcn_s_setprio(0);
    BARS();  // all LDS reads of buf (u&1) complete past this point

    // ---- Q4: stage (u+2) A-half0 (into this buffer - safe now), vmcnt(2) ----
    STAGE_HALF(u + 2, 0);
    VMCNT2();   // retires (u+1) h1,h2,h3 (h0 older) -> next tile fully resident
    BARS();
    __builtin_amdgcn_s_setprio(1);
#pragma unroll
    for (int mf = 0; mf < 4; mf++)
#pragma unroll
      for (int nf = 0; nf < 2; nf++)
#pragma unroll
        for (int ks = 0; ks < 2; ks++)
          acc[mf + 4][nf + 2] = __builtin_amdgcn_mfma_f32_16x16x32_bf16(a47[mf][ks], b23[nf][ks], acc[mf + 4][nf + 2], 0, 0, 0);
    __builtin_amdgcn_s_setprio(0);
    BARS();
  }
#undef STAGE_HALF

  // ---- split epilogue: n -> (head, q/k/v, d); d-range uniform per (wc,nf) ----
#pragma unroll
  for (int mf = 0; mf < 8; mf++)
#pragma unroll
    for (int nf = 0; nf < 4; nf++) {
      const int nn = (int)n0 + wc * 64 + nf * 16;
      const int h = nn / 384, tt = (nn >> 7) % 3;
      const int d = (nn & 127) + cbase;
      const int row0 = (int)m0 + wr * 128 + mf * 16 + rgrp * 4;
      const int bb = row0 >> 11;
      const int s0 = row0 & 2047;
      if (tt == 2) {
        ushort4 v;
        v.x = f2bf(acc[mf][nf][0]); v.y = f2bf(acc[mf][nf][1]);
        v.z = f2bf(acc[mf][nf][2]); v.w = f2bf(acc[mf][nf][3]);
        *(ushort4*)(Vg + ((size_t)(bb * HD + h) * DH + d) * SS + s0) = v;
      } else {
        unsigned short* dst = (tt == 0 ? Qg : Kg);
#pragma unroll
        for (int r = 0; r < 4; r++)
          dst[((size_t)(bb * HD + h) * SS + s0 + r) * DH + d] = f2bf(acc[mf][nf][r]);
      }
    }
}

// ---------------- 128x128 bf16 GEMM (round-8 proven) for out-proj: C f32 = A * Bt^T ----------------
__global__ __launch_bounds__(256) void gemm_out_k(const unsigned short* __restrict__ A,
                                                  const unsigned short* __restrict__ Bt,
                                                  float* __restrict__ C, int K, int ldc) {
  __shared__ __align__(16) unsigned short As[128 * 32];
  __shared__ __align__(16) unsigned short Bs[128 * 32];
  const int tid = threadIdx.x;
  const int lane = tid & 63, wid = tid >> 6;
  const int wr = wid >> 1, wc = wid & 1;
  const int cbase = lane & 15, rgrp = lane >> 4;
  const size_t m0 = (size_t)blockIdx.y * 128, n0 = (size_t)blockIdx.x * 128;

  f32x4 acc[4][4];
  const f32x4 z = {0.f, 0.f, 0.f, 0.f};
#pragma unroll
  for (int mf = 0; mf < 4; mf++)
#pragma unroll
    for (int nf = 0; nf < 4; nf++) acc[mf][nf] = z;

  const int nkt = K >> 5;
  for (int kt = 0; kt < nkt; ++kt) {
#pragma unroll
    for (int i = 0; i < 2; i++) {
      int idx = i * 256 + tid;
      int row = idx >> 2, cb = idx & 3;
      gload_lds16(A + (m0 + row) * K + (kt * 32 + cb * 8), As + idx * 8);
      gload_lds16(Bt + (n0 + row) * K + (kt * 32 + cb * 8), Bs + idx * 8);
    }
    __syncthreads();
    bfx8 af[4], bfr[4];
#pragma unroll
    for (int mf = 0; mf < 4; mf++)
      af[mf] = *(const bfx8*)(As + (wr * 64 + mf * 16 + cbase) * 32 + rgrp * 8);
#pragma unroll
    for (int nf = 0; nf < 4; nf++)
      bfr[nf] = *(const bfx8*)(Bs + (wc * 64 + nf * 16 + cbase) * 32 + rgrp * 8);
#pragma unroll
    for (int mf = 0; mf < 4; mf++)
#pragma unroll
      for (int nf = 0; nf < 4; nf++)
        acc[mf][nf] = __builtin_amdgcn_mfma_f32_16x16x32_bf16(af[mf], bfr[nf], acc[mf][nf], 0, 0, 0);
    __syncthreads();
  }

#pragma unroll
  for (int mf = 0; mf < 4; mf++)
#pragma unroll
    for (int nf = 0; nf < 4; nf++)
#pragma unroll
      for (int r = 0; r < 4; r++) {
        size_t row = m0 + wr * 64 + mf * 16 + rgrp * 4 + r;
        size_t col = n0 + wc * 64 + nf * 16 + cbase;
        C[row * ldc + col] = acc[mf][nf][r];
      }
}

// ---------------- flash attention (bf16, round-8 proven) ----------------
__global__ __launch_bounds__(256) void attn_fwd_k(const unsigned short* __restrict__ Qg,
                                                  const unsigned short* __restrict__ Kg,
                                                  const unsigned short* __restrict__ Vg,
                                                  unsigned short* __restrict__ ao) {
  __shared__ __align__(16) unsigned short Klds[64 * 128];
  __shared__ __align__(16) unsigned short Vt[128 * 64];
  __shared__ __align__(16) unsigned short Plds[4][16 * 64];
  const int tid = threadIdx.x;
  const int lane = tid & 63, wid = tid >> 6;
  const int cbase = lane & 15, rgrp = lane >> 4;

  const int bid = (int)blockIdx.x;
  const int bh = (bid & 7) * 4 + ((bid >> 3) & 3);
  const int qt = 31 - (bid >> 5);
  const int b = bh >> 4, h = bh & 15;
  const int qbase = qt * 64;

  const unsigned short* qp0 = Qg + (size_t)(b * HD + h) * SS * DH;
  const unsigned short* kp  = Kg + (size_t)(b * HD + h) * SS * DH;
  const unsigned short* vp  = Vg + (size_t)(b * HD + h) * DH * SS;
  const float scale = 0.08838834764831845f;
  const f32x4 z = {0.f, 0.f, 0.f, 0.f};

  bfx8 qf[4];
  {
    const unsigned short* qp = qp0 + (size_t)(qbase + wid * 16 + cbase) * DH;
#pragma unroll
    for (int ks = 0; ks < 4; ks++) qf[ks] = *(const bfx8*)(qp + ks * 32 + rgrp * 8);
  }

  float m_run[4], l_run[4];
  f32x4 o[8];
#pragma unroll
  for (int r = 0; r < 4; r++) { m_run[r] = -1e30f; l_run[r] = 0.f; }
#pragma unroll
  for (int mb = 0; mb < 8; mb++) o[mb] = z;

  const int ntiles = qt + 1;
  for (int t = 0; t < ntiles; ++t) {
    const int kvb = t * 64;
#pragma unroll
    for (int i = 0; i < 4; i++) {
      int idx = i * 256 + tid;
      int r = idx >> 4, bofs = (idx & 15) * 16;
      gload_lds16(kp + (size_t)(kvb + r) * DH + ((bofs ^ ((r & 7) << 4)) >> 1),
                  Klds + idx * 8);
    }
#pragma unroll
    for (int i = 0; i < 4; i++) {
      int idx = i * 256 + tid;
      int d = idx >> 3, bofs = (idx & 7) * 16;
      gload_lds16(vp + (size_t)d * SS + kvb + ((bofs ^ ((d & 7) << 4)) >> 1),
                  Vt + idx * 8);
    }
    __syncthreads();

    f32x4 s[4];
#pragma unroll
    for (int nf = 0; nf < 4; nf++) s[nf] = z;
#pragma unroll
    for (int nf = 0; nf < 4; nf++) {
      const int row = nf * 16 + cbase;
#pragma unroll
      for (int ks = 0; ks < 4; ks++) {
        bfx8 kf = *(const bfx8*)(Klds + ((row * 256 + ((ks * 64 + rgrp * 16) ^ ((row & 7) << 4))) >> 1));
        s[nf] = __builtin_amdgcn_mfma_f32_16x16x32_bf16(qf[ks], kf, s[nf], 0, 0, 0);
      }
    }

    const bool diag = (t == ntiles - 1);
    float p[4][4], alpha[4];
#pragma unroll
    for (int r = 0; r < 4; r++) {
      const int qi = qbase + wid * 16 + rgrp * 4 + r;
      float sv[4];
#pragma unroll
      for (int nf = 0; nf < 4; nf++) sv[nf] = s[nf][r] * scale;
      if (diag) {
#pragma unroll
        for (int nf = 0; nf < 4; nf++)
          if (kvb + nf * 16 + cbase > qi) sv[nf] = -1e30f;
      }
      float tm = fmaxf(fmaxf(sv[0], sv[1]), fmaxf(sv[2], sv[3]));
#pragma unroll
      for (int off = 1; off < 16; off <<= 1) tm = fmaxf(tm, __shfl_xor(tm, off));
      const float mnew = fmaxf(m_run[r], tm);
      float rs = 0.f;
#pragma unroll
      for (int nf = 0; nf < 4; nf++) { p[nf][r] = __expf(sv[nf] - mnew); rs += p[nf][r]; }
#pragma unroll
      for (int off = 1; off < 16; off <<= 1) rs += __shfl_xor(rs, off);
      alpha[r] = __expf(m_run[r] - mnew);
      l_run[r] = l_run[r] * alpha[r] + rs;
      m_run[r] = mnew;
    }
#pragma unroll
    for (int mb = 0; mb < 8; mb++)
#pragma unroll
      for (int r = 0; r < 4; r++) o[mb][r] *= alpha[r];

#pragma unroll
    for (int nf = 0; nf < 4; nf++)
#pragma unroll
      for (int r = 0; r < 4; r++) {
        const int row = rgrp * 4 + r;
        Plds[wid][(row * 128 + ((nf * 32 + cbase * 2) ^ ((row & 7) << 4))) >> 1] = f2bf(p[nf][r]);
      }
    bfx8 pf[2];
#pragma unroll
    for (int k2 = 0; k2 < 2; k2++)
      pf[k2] = *(const bfx8*)(&Plds[wid][(cbase * 128 + ((k2 * 64 + rgrp * 16) ^ ((cbase & 7) << 4))) >> 1]);

#pragma unroll
    for (int mb = 0; mb < 8; mb++) {
      const int d = mb * 16 + cbase;
#pragma unroll
      for (int k2 = 0; k2 < 2; k2++) {
        bfx8 vf = *(const bfx8*)(Vt + ((d * 128 + ((k2 * 64 + rgrp * 16) ^ ((d & 7) << 4))) >> 1));
        o[mb] = __builtin_amdgcn_mfma_f32_16x16x32_bf16(pf[k2], vf, o[mb], 0, 0, 0);
      }
    }
    __syncthreads();
  }

  float rinv[4];
#pragma unroll
  for (int r = 0; r < 4; r++) rinv[r] = 1.0f / l_run[r];
  const int qrow0 = qbase + wid * 16 + rgrp * 4;
#pragma unroll
  for (int mb = 0; mb < 8; mb++)
#pragma unroll
    for (int r = 0; r < 4; r++) {
      size_t idx = ((size_t)(b * SS + qrow0 + r)) * (size_t)DM + h * DH + mb * 16 + cbase;
      ao[idx] = f2bf(o[mb][r] * rinv[r]);
    }
}

extern "C" void kernel_launch(void* const* d_in, const int* in_sizes, int n_in,
                              void* d_out, int out_size, void* d_ws, size_t ws_size,
                              hipStream_t stream) {
  (void)in_sizes; (void)n_in; (void)out_size; (void)ws_size;
  const float* x     = (const float*)d_in[0];
  const float* w_in  = (const float*)d_in[1];
  const float* w_out = (const float*)d_in[2];
  float* out = (float*)d_out;

  char* ws = (char*)d_ws;
  unsigned short* Xb  = (unsigned short*)(ws);                     // 16 MB  [4096][2048]
  unsigned short* Wit = (unsigned short*)(ws + (16ull << 20));     // 24 MB  [6144][2048]
  unsigned short* Wot = (unsigned short*)(ws + (40ull << 20));     //  8 MB  [2048][2048]
  unsigned short* Qg  = (unsigned short*)(ws + (48ull << 20));     // 16 MB  [b][h][s][d]
  unsigned short* Kg  = (unsigned short*)(ws + (64ull << 20));     // 16 MB  [b][h][s][d]
  unsigned short* Vg  = (unsigned short*)(ws + (80ull << 20));     // 16 MB  [b][h][d][s]
  unsigned short* AO  = (unsigned short*)(ws + (96ull << 20));     // 16 MB  [4096][2048]

  f32_to_bf16_k<<<MTOT * DM / 4 / 256, 256, 0, stream>>>(x, Xb, MTOT * DM / 4);
  transpose_f32_bf16_k<<<dim3(NQKV / 32, DM / 32), 256, 0, stream>>>(w_in, Wit, DM, NQKV);
  transpose_f32_bf16_k<<<dim3(DM / 32, DM / 32), 256, 0, stream>>>(w_out, Wot, DM, DM);
  // QKV projection: 256x256 8-phase, grid 16m x 24n = 384 blocks x 512 threads
  gemm256_qkv_k<<<384, 512, 0, stream>>>(Xb, Wit, Qg, Kg, Vg, DM);
  // attention -> AO
  attn_fwd_k<<<1024, 256, 0, stream>>>(Qg, Kg, Vg, AO);
  // out = AO @ Wot^T (f32)
  gemm_out_k<<<dim3(DM / 128, MTOT / 128), 256, 0, stream>>>(AO, Wot, out, DM, DM);
}

// Round 11
// 294.253 us; speedup vs baseline: 1.2281x; 1.2281x over previous
//
#include <hip/hip_runtime.h>

// Problem constants
#define HD    16
#define DH    128
#define BB    2
#define SS    2048
#define DM    2048
#define NQKV  6144   // 3*HD*DH
#define MTOT  4096   // BB*SS

typedef short   bfx8  __attribute__((ext_vector_type(8)));   // 8 bf16 (4 VGPRs)
typedef float   f32x4 __attribute__((ext_vector_type(4)));

__device__ __forceinline__ unsigned short f2bf(float f) {
  union { float f; unsigned int u; } c; c.f = f;
  unsigned int u = c.u + 0x7FFFu + ((c.u >> 16) & 1u);
  return (unsigned short)(u >> 16);
}

__device__ __forceinline__ void gload_lds16(const unsigned short* g, unsigned short* l) {
  __builtin_amdgcn_global_load_lds(
      (const __attribute__((address_space(1))) unsigned int*)g,
      (__attribute__((address_space(3))) unsigned int*)l, 16, 0, 0);
}

// raw barrier fenced against compiler reordering (no vmcnt/lgkmcnt drain)
#define BARS() do { __builtin_amdgcn_sched_barrier(0); __builtin_amdgcn_s_barrier(); \
                    __builtin_amdgcn_sched_barrier(0); } while (0)
#define VMCNT2() do { asm volatile("s_waitcnt vmcnt(2)" ::: "memory"); \
                      __builtin_amdgcn_sched_barrier(0); } while (0)

// ---------------- f32 -> bf16 cast ----------------
__global__ __launch_bounds__(256) void f32_to_bf16_k(const float* __restrict__ in,
                                                     unsigned short* __restrict__ out, int n4) {
  int i = (blockIdx.x * 256 + threadIdx.x);
  if (i >= n4) return;
  const float4 v = *(const float4*)(in + (size_t)i * 4);
  ushort4 o;
  o.x = f2bf(v.x); o.y = f2bf(v.y); o.z = f2bf(v.z); o.w = f2bf(v.w);
  *(ushort4*)(out + (size_t)i * 4) = o;
}

// ---------------- f32 [R][C] -> bf16 [C][R] transpose ----------------
__global__ __launch_bounds__(256) void transpose_f32_bf16_k(const float* __restrict__ in,
                                                            unsigned short* __restrict__ out,
                                                            int R, int C) {
  __shared__ float t[32][33];
  const int c0 = blockIdx.x * 32, r0 = blockIdx.y * 32;
  const int tx = threadIdx.x & 31, ty = threadIdx.x >> 5;  // 32 x 8
#pragma unroll
  for (int i = 0; i < 4; i++) {
    int r = r0 + ty + i * 8;
    t[ty + i * 8][tx] = in[(size_t)r * C + c0 + tx];
  }
  __syncthreads();
#pragma unroll
  for (int i = 0; i < 4; i++) {
    int c = c0 + ty + i * 8;
    out[(size_t)c * R + r0 + tx] = f2bf(t[tx][ty + i * 8]);
  }
}

// ---------------- 256x256 8-phase bf16 GEMM for QKV (round-10, kept) ----------------
__global__ __launch_bounds__(512, 2) void gemm256_qkv_k(const unsigned short* __restrict__ A,
                                                        const unsigned short* __restrict__ Bt,
                                                        unsigned short* __restrict__ Qg,
                                                        unsigned short* __restrict__ Kg,
                                                        unsigned short* __restrict__ Vg,
                                                        int K) {
  __shared__ __align__(16) unsigned short Asb[2][256 * 64];  // 64 KB
  __shared__ __align__(16) unsigned short Bsb[2][256 * 64];  // 64 KB
  const int tid = threadIdx.x;
  const int lane = tid & 63, wid = tid >> 6;
  const int wr = wid >> 2, wc = wid & 3;            // 2 x 4 wave grid
  const int cbase = lane & 15, rgrp = lane >> 4;
  const int bid = (int)blockIdx.x;
  const int id = (bid & 7) * 48 + (bid >> 3);       // XCD-bijective (384 = 8*48)
  const int nb = id >> 4, mb = id & 15;
  const size_t m0 = (size_t)mb * 256, n0 = (size_t)nb * 256;
  const int nkt = K >> 6;

#define STAGE_HALF(u_, half_) do {                                                      \
    const int uc_ = ((u_) < nkt ? (u_) : (nkt - 1));                                    \
    unsigned short* ldsb_ = (((half_) < 2) ? &Asb[(u_) & 1][0] : &Bsb[(u_) & 1][0])     \
                            + ((half_) & 1) * (128 * 64);                               \
    const unsigned short* gb_ = (((half_) < 2)                                          \
        ? A  + (m0 + (size_t)((half_) & 1) * 128) * (size_t)K                           \
        : Bt + (n0 + (size_t)((half_) & 1) * 128) * (size_t)K);                         \
    _Pragma("unroll")                                                                   \
    for (int ld_ = 0; ld_ < 2; ld_++) {                                                 \
      const int idx_ = ld_ * 512 + tid;                                                 \
      const int row_ = idx_ >> 3, seg_ = idx_ & 7;                                      \
      gload_lds16(gb_ + (size_t)row_ * K + uc_ * 64 +                                   \
                      (((seg_ * 16) ^ ((row_ & 7) << 4)) >> 1),                         \
                  ldsb_ + idx_ * 8);                                                    \
    } } while (0)

  const int axor = (cbase & 7) << 4;
  int a_off[2], b_off[2];
#pragma unroll
  for (int ks = 0; ks < 2; ks++) {
    a_off[ks] = ((wr * 128 + cbase) * 128 + ((ks * 64 + rgrp * 16) ^ axor)) >> 1;
    b_off[ks] = ((wc * 64 + cbase) * 128 + ((ks * 64 + rgrp * 16) ^ axor)) >> 1;
  }

  f32x4 acc[8][4];
  const f32x4 z = {0.f, 0.f, 0.f, 0.f};
#pragma unroll
  for (int mf = 0; mf < 8; mf++)
#pragma unroll
    for (int nf = 0; nf < 4; nf++) acc[mf][nf] = z;

  STAGE_HALF(0, 0); STAGE_HALF(0, 1); STAGE_HALF(0, 2); STAGE_HALF(0, 3);
  STAGE_HALF(1, 0);
  VMCNT2();
  BARS();

#pragma unroll 1
  for (int u = 0; u < nkt; ++u) {
    const unsigned short* As_ = &Asb[u & 1][0];
    const unsigned short* Bs_ = &Bsb[u & 1][0];
    bfx8 a03[4][2], a47[4][2], b01[2][2], b23[2][2];

#pragma unroll
    for (int mf = 0; mf < 4; mf++)
#pragma unroll
      for (int ks = 0; ks < 2; ks++)
        a03[mf][ks] = *(const bfx8*)(As_ + a_off[ks] + mf * 1024);
#pragma unroll
    for (int nf = 0; nf < 2; nf++)
#pragma unroll
      for (int ks = 0; ks < 2; ks++)
        b01[nf][ks] = *(const bfx8*)(Bs_ + b_off[ks] + nf * 1024);
    STAGE_HALF(u + 1, 1);
    BARS();
    __builtin_amdgcn_s_setprio(1);
#pragma unroll
    for (int mf = 0; mf < 4; mf++)
#pragma unroll
      for (int nf = 0; nf < 2; nf++)
#pragma unroll
        for (int ks = 0; ks < 2; ks++)
          acc[mf][nf] = __builtin_amdgcn_mfma_f32_16x16x32_bf16(a03[mf][ks], b01[nf][ks], acc[mf][nf], 0, 0, 0);
    __builtin_amdgcn_s_setprio(0);
    BARS();

#pragma unroll
    for (int nf = 0; nf < 2; nf++)
#pragma unroll
      for (int ks = 0; ks < 2; ks++)
        b23[nf][ks] = *(const bfx8*)(Bs_ + b_off[ks] + (nf + 2) * 1024);
    STAGE_HALF(u + 1, 2);
    BARS();
    __builtin_amdgcn_s_setprio(1);
#pragma unroll
    for (int mf = 0; mf < 4; mf++)
#pragma unroll
      for (int nf = 0; nf < 2; nf++)
#pragma unroll
        for (int ks = 0; ks < 2; ks++)
          acc[mf][nf + 2] = __builtin_amdgcn_mfma_f32_16x16x32_bf16(a03[mf][ks], b23[nf][ks], acc[mf][nf + 2], 0, 0, 0);
    __builtin_amdgcn_s_setprio(0);
    BARS();

#pragma unroll
    for (int mf = 0; mf < 4; mf++)
#pragma unroll
      for (int ks = 0; ks < 2; ks++)
        a47[mf][ks] = *(const bfx8*)(As_ + a_off[ks] + (mf + 4) * 1024);
    STAGE_HALF(u + 1, 3);
    BARS();
    __builtin_amdgcn_s_setprio(1);
#pragma unroll
    for (int mf = 0; mf < 4; mf++)
#pragma unroll
      for (int nf = 0; nf < 2; nf++)
#pragma unroll
        for (int ks = 0; ks < 2; ks++)
          acc[mf + 4][nf] = __builtin_amdgcn_mfma_f32_16x16x32_bf16(a47[mf][ks], b01[nf][ks], acc[mf + 4][nf], 0, 0, 0);
    __builtin_amdgcn_s_setprio(0);
    BARS();

    STAGE_HALF(u + 2, 0);
    VMCNT2();
    BARS();
    __builtin_amdgcn_s_setprio(1);
#pragma unroll
    for (int mf = 0; mf < 4; mf++)
#pragma unroll
      for (int nf = 0; nf < 2; nf++)
#pragma unroll
        for (int ks = 0; ks < 2; ks++)
          acc[mf + 4][nf + 2] = __builtin_amdgcn_mfma_f32_16x16x32_bf16(a47[mf][ks], b23[nf][ks], acc[mf + 4][nf + 2], 0, 0, 0);
    __builtin_amdgcn_s_setprio(0);
    BARS();
  }
#undef STAGE_HALF

#pragma unroll
  for (int mf = 0; mf < 8; mf++)
#pragma unroll
    for (int nf = 0; nf < 4; nf++) {
      const int nn = (int)n0 + wc * 64 + nf * 16;
      const int h = nn / 384, tt = (nn >> 7) % 3;
      const int d = (nn & 127) + cbase;
      const int row0 = (int)m0 + wr * 128 + mf * 16 + rgrp * 4;
      const int bb = row0 >> 11;
      const int s0 = row0 & 2047;
      if (tt == 2) {
        ushort4 v;
        v.x = f2bf(acc[mf][nf][0]); v.y = f2bf(acc[mf][nf][1]);
        v.z = f2bf(acc[mf][nf][2]); v.w = f2bf(acc[mf][nf][3]);
        *(ushort4*)(Vg + ((size_t)(bb * HD + h) * DH + d) * SS + s0) = v;
      } else {
        unsigned short* dst = (tt == 0 ? Qg : Kg);
#pragma unroll
        for (int r = 0; r < 4; r++)
          dst[((size_t)(bb * HD + h) * SS + s0 + r) * DH + d] = f2bf(acc[mf][nf][r]);
      }
    }
}

// ---------------- 128x128 bf16 GEMM for out-proj: C f32 = A * Bt^T ----------------
__global__ __launch_bounds__(256) void gemm_out_k(const unsigned short* __restrict__ A,
                                                  const unsigned short* __restrict__ Bt,
                                                  float* __restrict__ C, int K, int ldc) {
  __shared__ __align__(16) unsigned short As[128 * 32];
  __shared__ __align__(16) unsigned short Bs[128 * 32];
  const int tid = threadIdx.x;
  const int lane = tid & 63, wid = tid >> 6;
  const int wr = wid >> 1, wc = wid & 1;
  const int cbase = lane & 15, rgrp = lane >> 4;
  const size_t m0 = (size_t)blockIdx.y * 128, n0 = (size_t)blockIdx.x * 128;

  f32x4 acc[4][4];
  const f32x4 z = {0.f, 0.f, 0.f, 0.f};
#pragma unroll
  for (int mf = 0; mf < 4; mf++)
#pragma unroll
    for (int nf = 0; nf < 4; nf++) acc[mf][nf] = z;

  const int nkt = K >> 5;
  for (int kt = 0; kt < nkt; ++kt) {
#pragma unroll
    for (int i = 0; i < 2; i++) {
      int idx = i * 256 + tid;
      int row = idx >> 2, cb = idx & 3;
      gload_lds16(A + (m0 + row) * K + (kt * 32 + cb * 8), As + idx * 8);
      gload_lds16(Bt + (n0 + row) * K + (kt * 32 + cb * 8), Bs + idx * 8);
    }
    __syncthreads();
    bfx8 af[4], bfr[4];
#pragma unroll
    for (int mf = 0; mf < 4; mf++)
      af[mf] = *(const bfx8*)(As + (wr * 64 + mf * 16 + cbase) * 32 + rgrp * 8);
#pragma unroll
    for (int nf = 0; nf < 4; nf++)
      bfr[nf] = *(const bfx8*)(Bs + (wc * 64 + nf * 16 + cbase) * 32 + rgrp * 8);
#pragma unroll
    for (int mf = 0; mf < 4; mf++)
#pragma unroll
      for (int nf = 0; nf < 4; nf++)
        acc[mf][nf] = __builtin_amdgcn_mfma_f32_16x16x32_bf16(af[mf], bfr[nf], acc[mf][nf], 0, 0, 0);
    __syncthreads();
  }

#pragma unroll
  for (int mf = 0; mf < 4; mf++)
#pragma unroll
    for (int nf = 0; nf < 4; nf++)
#pragma unroll
      for (int r = 0; r < 4; r++) {
        size_t row = m0 + wr * 64 + mf * 16 + rgrp * 4 + r;
        size_t col = n0 + wc * 64 + nf * 16 + cbase;
        C[row * ldc + col] = acc[mf][nf][r];
      }
}

// ---------------- flash attention (bf16, swapped-operand in-register softmax) ----------------
// 4 waves, 64 q/block (16 per wave), KVBLK=64, K/V double-buffered swizzled LDS.
// mfma(kf,qf) -> lane holds full P-row (q=cbase): softmax = in-lane reduce + 2 shuffles.
// mfma(vf,pf) -> O^T[d][q]; alpha/m/l scalar per lane. P routed via per-wave LDS (no barrier).
__global__ __launch_bounds__(256) void attn_fwd_k(const unsigned short* __restrict__ Qg,
                                                  const unsigned short* __restrict__ Kg,
                                                  const unsigned short* __restrict__ Vg,
                                                  unsigned short* __restrict__ ao) {
  __shared__ __align__(16) unsigned short Klds[2][64 * 128];   // 2 x 16 KB
  __shared__ __align__(16) unsigned short Vt[2][128 * 64];     // 2 x 16 KB
  __shared__ __align__(16) unsigned short Plds[4][16 * 64];    // 8 KB per-wave P rows
  const int tid = threadIdx.x;
  const int lane = tid & 63, wid = tid >> 6;
  const int cbase = lane & 15, rgrp = lane >> 4;
  const int cx = (cbase & 7) << 4;   // row-xor (byte) shared by P/V/K reads

  const int bid = (int)blockIdx.x;
  const int bh = (bid & 7) * 4 + ((bid >> 3) & 3);
  const int qt = 31 - (bid >> 5);
  const int b = bh >> 4, h = bh & 15;
  const int qbase = qt * 64;

  const unsigned short* qp0 = Qg + (size_t)(b * HD + h) * SS * DH;
  const unsigned short* kp  = Kg + (size_t)(b * HD + h) * SS * DH;
  const unsigned short* vp  = Vg + (size_t)(b * HD + h) * DH * SS;
  const float scale = 0.08838834764831845f;
  const f32x4 z = {0.f, 0.f, 0.f, 0.f};
  const int qi = qbase + wid * 16 + cbase;   // this lane's q-row

  // Q B-fragment (lane-fixed q = qi)
  bfx8 qf[4];
  {
    const unsigned short* qp = qp0 + (size_t)qi * DH;
#pragma unroll
    for (int ks = 0; ks < 4; ks++) qf[ks] = *(const bfx8*)(qp + ks * 32 + rgrp * 8);
  }

  float m_run = -1e30f, l_run = 0.f;
  f32x4 o[8];   // o[mb][r] = O[q=qi][d = mb*16 + rgrp*4 + r]
#pragma unroll
  for (int mb = 0; mb < 8; mb++) o[mb] = z;

#define STAGE_T(t_, s_) do {                                                        \
    const int kvb_ = (t_) * 64;                                                     \
    _Pragma("unroll")                                                               \
    for (int i_ = 0; i_ < 4; i_++) {                                                \
      int idx_ = i_ * 256 + tid;                                                    \
      int r_ = idx_ >> 4, bo_ = (idx_ & 15) * 16;                                   \
      gload_lds16(kp + (size_t)(kvb_ + r_) * DH + ((bo_ ^ ((r_ & 7) << 4)) >> 1),   \
                  &Klds[s_][idx_ * 8]);                                             \
    }                                                                               \
    _Pragma("unroll")                                                               \
    for (int i_ = 0; i_ < 4; i_++) {                                                \
      int idx_ = i_ * 256 + tid;                                                    \
      int d_ = idx_ >> 3, bo_ = (idx_ & 7) * 16;                                    \
      gload_lds16(vp + (size_t)d_ * SS + kvb_ + ((bo_ ^ ((d_ & 7) << 4)) >> 1),     \
                  &Vt[s_][idx_ * 8]);                                               \
    } } while (0)

  const int ntiles = qt + 1;
  STAGE_T(0, 0);
  __syncthreads();

  for (int t = 0; t < ntiles; ++t) {
    const int sel = t & 1;
    if (t + 1 < ntiles) STAGE_T(t + 1, sel ^ 1);
    const unsigned short* Ks_ = &Klds[sel][0];
    const unsigned short* Vs_ = &Vt[sel][0];
    const int kvb = t * 64;

    // S^T = mfma(K, Q): s[mf][r] = S[q=qi][kv = kvb + mf*16 + rgrp*4 + r]
    f32x4 s[4];
#pragma unroll
    for (int mf = 0; mf < 4; mf++) s[mf] = z;
#pragma unroll
    for (int mf = 0; mf < 4; mf++)
#pragma unroll
      for (int ks = 0; ks < 4; ks++) {
        bfx8 kf = *(const bfx8*)(Ks_ + (((mf * 16 + cbase) * 256 + ((ks * 64 + rgrp * 16) ^ cx)) >> 1));
        s[mf] = __builtin_amdgcn_mfma_f32_16x16x32_bf16(kf, qf[ks], s[mf], 0, 0, 0);
      }

    // scale + causal mask (diag tile only) — all values for ONE q-row, lane-local
    float sv[4][4];
    const bool diag = (t == ntiles - 1);
#pragma unroll
    for (int mf = 0; mf < 4; mf++)
#pragma unroll
      for (int r = 0; r < 4; r++) {
        float v = s[mf][r] * scale;
        if (diag && (kvb + mf * 16 + rgrp * 4 + r > qi)) v = -1e30f;
        sv[mf][r] = v;
      }
    // row max: in-lane 16 + cross-rgrp (2 shuffles)
    float tm = sv[0][0];
#pragma unroll
    for (int mf = 0; mf < 4; mf++)
#pragma unroll
      for (int r = 0; r < 4; r++) tm = fmaxf(tm, sv[mf][r]);
    tm = fmaxf(tm, __shfl_xor(tm, 16));
    tm = fmaxf(tm, __shfl_xor(tm, 32));
    const float mnew = fmaxf(m_run, tm);
    float p[4][4];
    float rs = 0.f;
#pragma unroll
    for (int mf = 0; mf < 4; mf++)
#pragma unroll
      for (int r = 0; r < 4; r++) { p[mf][r] = __expf(sv[mf][r] - mnew); rs += p[mf][r]; }
    rs += __shfl_xor(rs, 16);
    rs += __shfl_xor(rs, 32);
    const float alpha = __expf(m_run - mnew);
    l_run = l_run * alpha + rs;
    m_run = mnew;
#pragma unroll
    for (int mb = 0; mb < 8; mb++)
#pragma unroll
      for (int r = 0; r < 4; r++) o[mb][r] *= alpha;

    // P row (q=cbase within wave) -> per-wave LDS (swizzled u32 pair writes), no barrier
#pragma unroll
    for (int mf = 0; mf < 4; mf++)
#pragma unroll
      for (int rr = 0; rr < 2; rr++) {
        unsigned int pp = (unsigned int)f2bf(p[mf][2 * rr]) |
                          ((unsigned int)f2bf(p[mf][2 * rr + 1]) << 16);
        *(unsigned int*)((char*)&Plds[wid][0] +
                         (cbase * 128 + ((mf * 32 + rgrp * 8 + rr * 4) ^ cx))) = pp;
      }
    bfx8 pf[2];
#pragma unroll
    for (int k2 = 0; k2 < 2; k2++)
      pf[k2] = *(const bfx8*)((const char*)&Plds[wid][0] +
                              (cbase * 128 + ((k2 * 64 + rgrp * 16) ^ cx)));

    // O^T += mfma(V^T, P): o[mb][r] += sum_kv V[kv][d] P[q][kv]
#pragma unroll
    for (int mb = 0; mb < 8; mb++)
#pragma unroll
      for (int k2 = 0; k2 < 2; k2++) {
        bfx8 vf = *(const bfx8*)(Vs_ + (((mb * 16 + cbase) * 128 + ((k2 * 64 + rgrp * 16) ^ cx)) >> 1));
        o[mb] = __builtin_amdgcn_mfma_f32_16x16x32_bf16(vf, pf[k2], o[mb], 0, 0, 0);
      }
    __syncthreads();   // drains vmcnt: next buffer staged; all reads of 'sel' done
  }
#undef STAGE_T

  // epilogue: lane owns row q=qi, d-range contiguous per mb -> ushort4 stores
  const float rinv = 1.0f / l_run;
  unsigned short* aop = ao + ((size_t)(b * SS + qi)) * DM + h * DH + rgrp * 4;
#pragma unroll
  for (int mb = 0; mb < 8; mb++) {
    ushort4 v;
    v.x = f2bf(o[mb][0] * rinv); v.y = f2bf(o[mb][1] * rinv);
    v.z = f2bf(o[mb][2] * rinv); v.w = f2bf(o[mb][3] * rinv);
    *(ushort4*)(aop + mb * 16) = v;
  }
}

extern "C" void kernel_launch(void* const* d_in, const int* in_sizes, int n_in,
                              void* d_out, int out_size, void* d_ws, size_t ws_size,
                              hipStream_t stream) {
  (void)in_sizes; (void)n_in; (void)out_size; (void)ws_size;
  const float* x     = (const float*)d_in[0];
  const float* w_in  = (const float*)d_in[1];
  const float* w_out = (const float*)d_in[2];
  float* out = (float*)d_out;

  char* ws = (char*)d_ws;
  unsigned short* Xb  = (unsigned short*)(ws);                     // 16 MB  [4096][2048]
  unsigned short* Wit = (unsigned short*)(ws + (16ull << 20));     // 24 MB  [6144][2048]
  unsigned short* Wot = (unsigned short*)(ws + (40ull << 20));     //  8 MB  [2048][2048]
  unsigned short* Qg  = (unsigned short*)(ws + (48ull << 20));     // 16 MB  [b][h][s][d]
  unsigned short* Kg  = (unsigned short*)(ws + (64ull << 20));     // 16 MB  [b][h][s][d]
  unsigned short* Vg  = (unsigned short*)(ws + (80ull << 20));     // 16 MB  [b][h][d][s]
  unsigned short* AO  = (unsigned short*)(ws + (96ull << 20));     // 16 MB  [4096][2048]

  f32_to_bf16_k<<<MTOT * DM / 4 / 256, 256, 0, stream>>>(x, Xb, MTOT * DM / 4);
  transpose_f32_bf16_k<<<dim3(NQKV / 32, DM / 32), 256, 0, stream>>>(w_in, Wit, DM, NQKV);
  transpose_f32_bf16_k<<<dim3(DM / 32, DM / 32), 256, 0, stream>>>(w_out, Wot, DM, DM);
  gemm256_qkv_k<<<384, 512, 0, stream>>>(Xb, Wit, Qg, Kg, Vg, DM);
  attn_fwd_k<<<1024, 256, 0, stream>>>(Qg, Kg, Vg, AO);
  gemm_out_k<<<dim3(DM / 128, MTOT / 128), 256, 0, stream>>>(AO, Wot, out, DM, DM);
}

// Round 12
// 279.292 us; speedup vs baseline: 1.2939x; 1.0536x over previous
//
#include <hip/hip_runtime.h>

// Problem constants
#define HD    16
#define DH    128
#define BB    2
#define SS    2048
#define DM    2048
#define NQKV  6144   // 3*HD*DH
#define MTOT  4096   // BB*SS

typedef short   bfx8  __attribute__((ext_vector_type(8)));   // 8 bf16 (4 VGPRs)
typedef float   f32x4 __attribute__((ext_vector_type(4)));

__device__ __forceinline__ unsigned short f2bf(float f) {
  union { float f; unsigned int u; } c; c.f = f;
  unsigned int u = c.u + 0x7FFFu + ((c.u >> 16) & 1u);
  return (unsigned short)(u >> 16);
}

__device__ __forceinline__ void gload_lds16(const unsigned short* g, unsigned short* l) {
  __builtin_amdgcn_global_load_lds(
      (const __attribute__((address_space(1))) unsigned int*)g,
      (__attribute__((address_space(3))) unsigned int*)l, 16, 0, 0);
}

// raw barrier fenced against compiler reordering (no vmcnt/lgkmcnt drain)
#define BARS() do { __builtin_amdgcn_sched_barrier(0); __builtin_amdgcn_s_barrier(); \
                    __builtin_amdgcn_sched_barrier(0); } while (0)
#define VMCNT8() do { asm volatile("s_waitcnt vmcnt(8)" ::: "memory"); \
                      __builtin_amdgcn_sched_barrier(0); } while (0)

// ---------------- f32 -> bf16 cast ----------------
__global__ __launch_bounds__(256) void f32_to_bf16_k(const float* __restrict__ in,
                                                     unsigned short* __restrict__ out, int n4) {
  int i = (blockIdx.x * 256 + threadIdx.x);
  if (i >= n4) return;
  const float4 v = *(const float4*)(in + (size_t)i * 4);
  ushort4 o;
  o.x = f2bf(v.x); o.y = f2bf(v.y); o.z = f2bf(v.z); o.w = f2bf(v.w);
  *(ushort4*)(out + (size_t)i * 4) = o;
}

// ---------------- f32 [R][C] -> bf16 [C][R] transpose ----------------
__global__ __launch_bounds__(256) void transpose_f32_bf16_k(const float* __restrict__ in,
                                                            unsigned short* __restrict__ out,
                                                            int R, int C) {
  __shared__ float t[32][33];
  const int c0 = blockIdx.x * 32, r0 = blockIdx.y * 32;
  const int tx = threadIdx.x & 31, ty = threadIdx.x >> 5;  // 32 x 8
#pragma unroll
  for (int i = 0; i < 4; i++) {
    int r = r0 + ty + i * 8;
    t[ty + i * 8][tx] = in[(size_t)r * C + c0 + tx];
  }
  __syncthreads();
#pragma unroll
  for (int i = 0; i < 4; i++) {
    int c = c0 + ty + i * 8;
    out[(size_t)c * R + r0 + tx] = f2bf(t[tx][ty + i * 8]);
  }
}

// ---------------- 256x256 8-phase bf16 GEMM for QKV, 2-tile-lookahead pipeline ----------------
// 8 waves (2M x 4N), BK=64, double-buffered swizzled LDS (128 KB).
// Read lifetimes: B-halves consumed by end of ph2, A-halves by end of ph3 ->
// stage tile t+2 B at ph3, A at ph4 (same buffer as t, regions already dead).
// vmcnt(8) once per tile at ph4: retires all of tile t+1, leaves t+2's 8 loads in flight.
__global__ __launch_bounds__(512, 2) void gemm256_qkv_k(const unsigned short* __restrict__ A,
                                                        const unsigned short* __restrict__ Bt,
                                                        unsigned short* __restrict__ Qg,
                                                        unsigned short* __restrict__ Kg,
                                                        unsigned short* __restrict__ Vg,
                                                        int K) {
  __shared__ __align__(16) unsigned short Asb[2][256 * 64];  // 64 KB
  __shared__ __align__(16) unsigned short Bsb[2][256 * 64];  // 64 KB
  const int tid = threadIdx.x;
  const int lane = tid & 63, wid = tid >> 6;
  const int wr = wid >> 2, wc = wid & 3;            // 2 x 4 wave grid
  const int cbase = lane & 15, rgrp = lane >> 4;
  const int bid = (int)blockIdx.x;
  const int id = (bid & 7) * 48 + (bid >> 3);       // XCD-bijective (384 = 8*48)
  const int nb = id >> 4, mb = id & 15;
  const size_t m0 = (size_t)mb * 256, n0 = (size_t)nb * 256;
  const int nkt = K >> 6;

  // half: 0=A rows 0-127, 1=A rows 128-255, 2=B rows 0-127, 3=B rows 128-255.
#define STAGE_HALF(u_, half_) do {                                                      \
    const int uc_ = ((u_) < nkt ? (u_) : (nkt - 1));                                    \
    unsigned short* ldsb_ = (((half_) < 2) ? &Asb[(u_) & 1][0] : &Bsb[(u_) & 1][0])     \
                            + ((half_) & 1) * (128 * 64);                               \
    const unsigned short* gb_ = (((half_) < 2)                                          \
        ? A  + (m0 + (size_t)((half_) & 1) * 128) * (size_t)K                           \
        : Bt + (n0 + (size_t)((half_) & 1) * 128) * (size_t)K);                         \
    _Pragma("unroll")                                                                   \
    for (int ld_ = 0; ld_ < 2; ld_++) {                                                 \
      const int idx_ = ld_ * 512 + tid;                                                 \
      const int row_ = idx_ >> 3, seg_ = idx_ & 7;                                      \
      gload_lds16(gb_ + (size_t)row_ * K + uc_ * 64 +                                   \
                      (((seg_ * 16) ^ ((row_ & 7) << 4)) >> 1),                         \
                  ldsb_ + idx_ * 8);                                                    \
    } } while (0)

  const int axor = (cbase & 7) << 4;
  int a_off[2], b_off[2];
#pragma unroll
  for (int ks = 0; ks < 2; ks++) {
    a_off[ks] = ((wr * 128 + cbase) * 128 + ((ks * 64 + rgrp * 16) ^ axor)) >> 1;
    b_off[ks] = ((wc * 64 + cbase) * 128 + ((ks * 64 + rgrp * 16) ^ axor)) >> 1;
  }

  f32x4 acc[8][4];
  const f32x4 z = {0.f, 0.f, 0.f, 0.f};
#pragma unroll
  for (int mf = 0; mf < 8; mf++)
#pragma unroll
    for (int nf = 0; nf < 4; nf++) acc[mf][nf] = z;

  // prologue: stage tiles 0 and 1 fully (16 loads); vmcnt(8) -> tile 0 landed
  STAGE_HALF(0, 2); STAGE_HALF(0, 3); STAGE_HALF(0, 0); STAGE_HALF(0, 1);
  STAGE_HALF(1, 2); STAGE_HALF(1, 3); STAGE_HALF(1, 0); STAGE_HALF(1, 1);
  VMCNT8();
  BARS();

#pragma unroll 1
  for (int u = 0; u < nkt; ++u) {
    const unsigned short* As_ = &Asb[u & 1][0];
    const unsigned short* Bs_ = &Bsb[u & 1][0];
    bfx8 a03[4][2], a47[4][2], b01[2][2], b23[2][2];

    // ---- ph1: read a03 + b01; MFMA Q1 (mf0-3, nf0-1) ----
#pragma unroll
    for (int mf = 0; mf < 4; mf++)
#pragma unroll
      for (int ks = 0; ks < 2; ks++)
        a03[mf][ks] = *(const bfx8*)(As_ + a_off[ks] + mf * 1024);
#pragma unroll
    for (int nf = 0; nf < 2; nf++)
#pragma unroll
      for (int ks = 0; ks < 2; ks++)
        b01[nf][ks] = *(const bfx8*)(Bs_ + b_off[ks] + nf * 1024);
    BARS();
    __builtin_amdgcn_s_setprio(1);
#pragma unroll
    for (int mf = 0; mf < 4; mf++)
#pragma unroll
      for (int nf = 0; nf < 2; nf++)
#pragma unroll
        for (int ks = 0; ks < 2; ks++)
          acc[mf][nf] = __builtin_amdgcn_mfma_f32_16x16x32_bf16(a03[mf][ks], b01[nf][ks], acc[mf][nf], 0, 0, 0);
    __builtin_amdgcn_s_setprio(0);
    BARS();

    // ---- ph2: read b23; MFMA Q2 (mf0-3, nf2-3). After this, B-halves of buf u are dead ----
#pragma unroll
    for (int nf = 0; nf < 2; nf++)
#pragma unroll
      for (int ks = 0; ks < 2; ks++)
        b23[nf][ks] = *(const bfx8*)(Bs_ + b_off[ks] + (nf + 2) * 1024);
    BARS();
    __builtin_amdgcn_s_setprio(1);
#pragma unroll
    for (int mf = 0; mf < 4; mf++)
#pragma unroll
      for (int nf = 0; nf < 2; nf++)
#pragma unroll
        for (int ks = 0; ks < 2; ks++)
          acc[mf][nf + 2] = __builtin_amdgcn_mfma_f32_16x16x32_bf16(a03[mf][ks], b23[nf][ks], acc[mf][nf + 2], 0, 0, 0);
    __builtin_amdgcn_s_setprio(0);
    BARS();

    // ---- ph3: read a47; stage tile u+2 B-halves (dead region); MFMA Q3 (mf4-7, nf0-1) ----
#pragma unroll
    for (int mf = 0; mf < 4; mf++)
#pragma unroll
      for (int ks = 0; ks < 2; ks++)
        a47[mf][ks] = *(const bfx8*)(As_ + a_off[ks] + (mf + 4) * 1024);
    STAGE_HALF(u + 2, 2);
    STAGE_HALF(u + 2, 3);
    BARS();
    __builtin_amdgcn_s_setprio(1);
#pragma unroll
    for (int mf = 0; mf < 4; mf++)
#pragma unroll
      for (int nf = 0; nf < 2; nf++)
#pragma unroll
        for (int ks = 0; ks < 2; ks++)
          acc[mf + 4][nf] = __builtin_amdgcn_mfma_f32_16x16x32_bf16(a47[mf][ks], b01[nf][ks], acc[mf + 4][nf], 0, 0, 0);
    __builtin_amdgcn_s_setprio(0);
    BARS();

    // ---- ph4: stage tile u+2 A-halves (dead region); vmcnt(8) -> tile u+1 resident;
    //          MFMA Q4 (mf4-7, nf2-3) ----
    STAGE_HALF(u + 2, 0);
    STAGE_HALF(u + 2, 1);
    VMCNT8();
    BARS();
    __builtin_amdgcn_s_setprio(1);
#pragma unroll
    for (int mf = 0; mf < 4; mf++)
#pragma unroll
      for (int nf = 0; nf < 2; nf++)
#pragma unroll
        for (int ks = 0; ks < 2; ks++)
          acc[mf + 4][nf + 2] = __builtin_amdgcn_mfma_f32_16x16x32_bf16(a47[mf][ks], b23[nf][ks], acc[mf + 4][nf + 2], 0, 0, 0);
    __builtin_amdgcn_s_setprio(0);
    BARS();
  }
#undef STAGE_HALF

  // ---- split epilogue: n -> (head, q/k/v, d) ----
#pragma unroll
  for (int mf = 0; mf < 8; mf++)
#pragma unroll
    for (int nf = 0; nf < 4; nf++) {
      const int nn = (int)n0 + wc * 64 + nf * 16;
      const int h = nn / 384, tt = (nn >> 7) % 3;
      const int d = (nn & 127) + cbase;
      const int row0 = (int)m0 + wr * 128 + mf * 16 + rgrp * 4;
      const int bb = row0 >> 11;
      const int s0 = row0 & 2047;
      if (tt == 2) {
        ushort4 v;
        v.x = f2bf(acc[mf][nf][0]); v.y = f2bf(acc[mf][nf][1]);
        v.z = f2bf(acc[mf][nf][2]); v.w = f2bf(acc[mf][nf][3]);
        *(ushort4*)(Vg + ((size_t)(bb * HD + h) * DH + d) * SS + s0) = v;
      } else {
        unsigned short* dst = (tt == 0 ? Qg : Kg);
#pragma unroll
        for (int r = 0; r < 4; r++)
          dst[((size_t)(bb * HD + h) * SS + s0 + r) * DH + d] = f2bf(acc[mf][nf][r]);
      }
    }
}

// ---------------- 128x128 bf16 GEMM for out-proj: C f32 = A * Bt^T ----------------
__global__ __launch_bounds__(256) void gemm_out_k(const unsigned short* __restrict__ A,
                                                  const unsigned short* __restrict__ Bt,
                                                  float* __restrict__ C, int K, int ldc) {
  __shared__ __align__(16) unsigned short As[128 * 32];
  __shared__ __align__(16) unsigned short Bs[128 * 32];
  const int tid = threadIdx.x;
  const int lane = tid & 63, wid = tid >> 6;
  const int wr = wid >> 1, wc = wid & 1;
  const int cbase = lane & 15, rgrp = lane >> 4;
  const size_t m0 = (size_t)blockIdx.y * 128, n0 = (size_t)blockIdx.x * 128;

  f32x4 acc[4][4];
  const f32x4 z = {0.f, 0.f, 0.f, 0.f};
#pragma unroll
  for (int mf = 0; mf < 4; mf++)
#pragma unroll
    for (int nf = 0; nf < 4; nf++) acc[mf][nf] = z;

  const int nkt = K >> 5;
  for (int kt = 0; kt < nkt; ++kt) {
#pragma unroll
    for (int i = 0; i < 2; i++) {
      int idx = i * 256 + tid;
      int row = idx >> 2, cb = idx & 3;
      gload_lds16(A + (m0 + row) * K + (kt * 32 + cb * 8), As + idx * 8);
      gload_lds16(Bt + (n0 + row) * K + (kt * 32 + cb * 8), Bs + idx * 8);
    }
    __syncthreads();
    bfx8 af[4], bfr[4];
#pragma unroll
    for (int mf = 0; mf < 4; mf++)
      af[mf] = *(const bfx8*)(As + (wr * 64 + mf * 16 + cbase) * 32 + rgrp * 8);
#pragma unroll
    for (int nf = 0; nf < 4; nf++)
      bfr[nf] = *(const bfx8*)(Bs + (wc * 64 + nf * 16 + cbase) * 32 + rgrp * 8);
#pragma unroll
    for (int mf = 0; mf < 4; mf++)
#pragma unroll
      for (int nf = 0; nf < 4; nf++)
        acc[mf][nf] = __builtin_amdgcn_mfma_f32_16x16x32_bf16(af[mf], bfr[nf], acc[mf][nf], 0, 0, 0);
    __syncthreads();
  }

#pragma unroll
  for (int mf = 0; mf < 4; mf++)
#pragma unroll
    for (int nf = 0; nf < 4; nf++)
#pragma unroll
      for (int r = 0; r < 4; r++) {
        size_t row = m0 + wr * 64 + mf * 16 + rgrp * 4 + r;
        size_t col = n0 + wc * 64 + nf * 16 + cbase;
        C[row * ldc + col] = acc[mf][nf][r];
      }
}

// ---------------- flash attention (bf16, swapped-operand in-register softmax) ----------------
__global__ __launch_bounds__(256) void attn_fwd_k(const unsigned short* __restrict__ Qg,
                                                  const unsigned short* __restrict__ Kg,
                                                  const unsigned short* __restrict__ Vg,
                                                  unsigned short* __restrict__ ao) {
  __shared__ __align__(16) unsigned short Klds[2][64 * 128];   // 2 x 16 KB
  __shared__ __align__(16) unsigned short Vt[2][128 * 64];     // 2 x 16 KB
  __shared__ __align__(16) unsigned short Plds[4][16 * 64];    // 8 KB per-wave P rows
  const int tid = threadIdx.x;
  const int lane = tid & 63, wid = tid >> 6;
  const int cbase = lane & 15, rgrp = lane >> 4;
  const int cx = (cbase & 7) << 4;

  const int bid = (int)blockIdx.x;
  const int bh = (bid & 7) * 4 + ((bid >> 3) & 3);
  const int qt = 31 - (bid >> 5);
  const int b = bh >> 4, h = bh & 15;
  const int qbase = qt * 64;

  const unsigned short* qp0 = Qg + (size_t)(b * HD + h) * SS * DH;
  const unsigned short* kp  = Kg + (size_t)(b * HD + h) * SS * DH;
  const unsigned short* vp  = Vg + (size_t)(b * HD + h) * DH * SS;
  const float scale = 0.08838834764831845f;
  const f32x4 z = {0.f, 0.f, 0.f, 0.f};
  const int qi = qbase + wid * 16 + cbase;

  bfx8 qf[4];
  {
    const unsigned short* qp = qp0 + (size_t)qi * DH;
#pragma unroll
    for (int ks = 0; ks < 4; ks++) qf[ks] = *(const bfx8*)(qp + ks * 32 + rgrp * 8);
  }

  float m_run = -1e30f, l_run = 0.f;
  f32x4 o[8];
#pragma unroll
  for (int mb = 0; mb < 8; mb++) o[mb] = z;

#define STAGE_T(t_, s_) do {                                                        \
    const int kvb_ = (t_) * 64;                                                     \
    _Pragma("unroll")                                                               \
    for (int i_ = 0; i_ < 4; i_++) {                                                \
      int idx_ = i_ * 256 + tid;                                                    \
      int r_ = idx_ >> 4, bo_ = (idx_ & 15) * 16;                                   \
      gload_lds16(kp + (size_t)(kvb_ + r_) * DH + ((bo_ ^ ((r_ & 7) << 4)) >> 1),   \
                  &Klds[s_][idx_ * 8]);                                             \
    }                                                                               \
    _Pragma("unroll")                                                               \
    for (int i_ = 0; i_ < 4; i_++) {                                                \
      int idx_ = i_ * 256 + tid;                                                    \
      int d_ = idx_ >> 3, bo_ = (idx_ & 7) * 16;                                    \
      gload_lds16(vp + (size_t)d_ * SS + kvb_ + ((bo_ ^ ((d_ & 7) << 4)) >> 1),     \
                  &Vt[s_][idx_ * 8]);                                               \
    } } while (0)

  const int ntiles = qt + 1;
  STAGE_T(0, 0);
  __syncthreads();

  for (int t = 0; t < ntiles; ++t) {
    const int sel = t & 1;
    if (t + 1 < ntiles) STAGE_T(t + 1, sel ^ 1);
    const unsigned short* Ks_ = &Klds[sel][0];
    const unsigned short* Vs_ = &Vt[sel][0];
    const int kvb = t * 64;

    f32x4 s[4];
#pragma unroll
    for (int mf = 0; mf < 4; mf++) s[mf] = z;
#pragma unroll
    for (int mf = 0; mf < 4; mf++)
#pragma unroll
      for (int ks = 0; ks < 4; ks++) {
        bfx8 kf = *(const bfx8*)(Ks_ + (((mf * 16 + cbase) * 256 + ((ks * 64 + rgrp * 16) ^ cx)) >> 1));
        s[mf] = __builtin_amdgcn_mfma_f32_16x16x32_bf16(kf, qf[ks], s[mf], 0, 0, 0);
      }

    float sv[4][4];
    const bool diag = (t == ntiles - 1);
#pragma unroll
    for (int mf = 0; mf < 4; mf++)
#pragma unroll
      for (int r = 0; r < 4; r++) {
        float v = s[mf][r] * scale;
        if (diag && (kvb + mf * 16 + rgrp * 4 + r > qi)) v = -1e30f;
        sv[mf][r] = v;
      }
    float tm = sv[0][0];
#pragma unroll
    for (int mf = 0; mf < 4; mf++)
#pragma unroll
      for (int r = 0; r < 4; r++) tm = fmaxf(tm, sv[mf][r]);
    tm = fmaxf(tm, __shfl_xor(tm, 16));
    tm = fmaxf(tm, __shfl_xor(tm, 32));
    const float mnew = fmaxf(m_run, tm);
    float p[4][4];
    float rs = 0.f;
#pragma unroll
    for (int mf = 0; mf < 4; mf++)
#pragma unroll
      for (int r = 0; r < 4; r++) { p[mf][r] = __expf(sv[mf][r] - mnew); rs += p[mf][r]; }
    rs += __shfl_xor(rs, 16);
    rs += __shfl_xor(rs, 32);
    const float alpha = __expf(m_run - mnew);
    l_run = l_run * alpha + rs;
    m_run = mnew;
#pragma unroll
    for (int mb = 0; mb < 8; mb++)
#pragma unroll
      for (int r = 0; r < 4; r++) o[mb][r] *= alpha;

#pragma unroll
    for (int mf = 0; mf < 4; mf++)
#pragma unroll
      for (int rr = 0; rr < 2; rr++) {
        unsigned int pp = (unsigned int)f2bf(p[mf][2 * rr]) |
                          ((unsigned int)f2bf(p[mf][2 * rr + 1]) << 16);
        *(unsigned int*)((char*)&Plds[wid][0] +
                         (cbase * 128 + ((mf * 32 + rgrp * 8 + rr * 4) ^ cx))) = pp;
      }
    bfx8 pf[2];
#pragma unroll
    for (int k2 = 0; k2 < 2; k2++)
      pf[k2] = *(const bfx8*)((const char*)&Plds[wid][0] +
                              (cbase * 128 + ((k2 * 64 + rgrp * 16) ^ cx)));

#pragma unroll
    for (int mb = 0; mb < 8; mb++)
#pragma unroll
      for (int k2 = 0; k2 < 2; k2++) {
        bfx8 vf = *(const bfx8*)(Vs_ + (((mb * 16 + cbase) * 128 + ((k2 * 64 + rgrp * 16) ^ cx)) >> 1));
        o[mb] = __builtin_amdgcn_mfma_f32_16x16x32_bf16(vf, pf[k2], o[mb], 0, 0, 0);
      }
    __syncthreads();
  }
#undef STAGE_T

  const float rinv = 1.0f / l_run;
  unsigned short* aop = ao + ((size_t)(b * SS + qi)) * DM + h * DH + rgrp * 4;
#pragma unroll
  for (int mb = 0; mb < 8; mb++) {
    ushort4 v;
    v.x = f2bf(o[mb][0] * rinv); v.y = f2bf(o[mb][1] * rinv);
    v.z = f2bf(o[mb][2] * rinv); v.w = f2bf(o[mb][3] * rinv);
    *(ushort4*)(aop + mb * 16) = v;
  }
}

extern "C" void kernel_launch(void* const* d_in, const int* in_sizes, int n_in,
                              void* d_out, int out_size, void* d_ws, size_t ws_size,
                              hipStream_t stream) {
  (void)in_sizes; (void)n_in; (void)out_size; (void)ws_size;
  const float* x     = (const float*)d_in[0];
  const float* w_in  = (const float*)d_in[1];
  const float* w_out = (const float*)d_in[2];
  float* out = (float*)d_out;

  char* ws = (char*)d_ws;
  unsigned short* Xb  = (unsigned short*)(ws);                     // 16 MB  [4096][2048]
  unsigned short* Wit = (unsigned short*)(ws + (16ull << 20));     // 24 MB  [6144][2048]
  unsigned short* Wot = (unsigned short*)(ws + (40ull << 20));     //  8 MB  [2048][2048]
  unsigned short* Qg  = (unsigned short*)(ws + (48ull << 20));     // 16 MB  [b][h][s][d]
  unsigned short* Kg  = (unsigned short*)(ws + (64ull << 20));     // 16 MB  [b][h][s][d]
  unsigned short* Vg  = (unsigned short*)(ws + (80ull << 20));     // 16 MB  [b][h][d][s]
  unsigned short* AO  = (unsigned short*)(ws + (96ull << 20));     // 16 MB  [4096][2048]

  f32_to_bf16_k<<<MTOT * DM / 4 / 256, 256, 0, stream>>>(x, Xb, MTOT * DM / 4);
  transpose_f32_bf16_k<<<dim3(NQKV / 32, DM / 32), 256, 0, stream>>>(w_in, Wit, DM, NQKV);
  transpose_f32_bf16_k<<<dim3(DM / 32, DM / 32), 256, 0, stream>>>(w_out, Wot, DM, DM);
  gemm256_qkv_k<<<384, 512, 0, stream>>>(Xb, Wit, Qg, Kg, Vg, DM);
  attn_fwd_k<<<1024, 256, 0, stream>>>(Qg, Kg, Vg, AO);
  gemm_out_k<<<dim3(DM / 128, MTOT / 128), 256, 0, stream>>>(AO, Wot, out, DM, DM);
}

// Round 13
// 273.059 us; speedup vs baseline: 1.3234x; 1.0228x over previous
//
#include <hip/hip_runtime.h>

// Problem constants
#define HD    16
#define DH    128
#define BB    2
#define SS    2048
#define DM    2048
#define NQKV  6144   // 3*HD*DH
#define MTOT  4096   // BB*SS

typedef short   bfx8  __attribute__((ext_vector_type(8)));   // 8 bf16 (4 VGPRs)
typedef float   f32x4 __attribute__((ext_vector_type(4)));

__device__ __forceinline__ unsigned short f2bf(float f) {
  union { float f; unsigned int u; } c; c.f = f;
  unsigned int u = c.u + 0x7FFFu + ((c.u >> 16) & 1u);
  return (unsigned short)(u >> 16);
}

__device__ __forceinline__ void gload_lds16(const unsigned short* g, unsigned short* l) {
  __builtin_amdgcn_global_load_lds(
      (const __attribute__((address_space(1))) unsigned int*)g,
      (__attribute__((address_space(3))) unsigned int*)l, 16, 0, 0);
}

// raw barrier fenced against compiler reordering (no vmcnt/lgkmcnt drain)
#define BARS() do { __builtin_amdgcn_sched_barrier(0); __builtin_amdgcn_s_barrier(); \
                    __builtin_amdgcn_sched_barrier(0); } while (0)
#define VMCNT8() do { asm volatile("s_waitcnt vmcnt(8)" ::: "memory"); \
                      __builtin_amdgcn_sched_barrier(0); } while (0)

// ---------------- f32 -> bf16 cast ----------------
__global__ __launch_bounds__(256) void f32_to_bf16_k(const float* __restrict__ in,
                                                     unsigned short* __restrict__ out, int n4) {
  int i = (blockIdx.x * 256 + threadIdx.x);
  if (i >= n4) return;
  const float4 v = *(const float4*)(in + (size_t)i * 4);
  ushort4 o;
  o.x = f2bf(v.x); o.y = f2bf(v.y); o.z = f2bf(v.z); o.w = f2bf(v.w);
  *(ushort4*)(out + (size_t)i * 4) = o;
}

// ---------------- f32 [R][C] -> bf16 [C][R] transpose ----------------
__global__ __launch_bounds__(256) void transpose_f32_bf16_k(const float* __restrict__ in,
                                                            unsigned short* __restrict__ out,
                                                            int R, int C) {
  __shared__ float t[32][33];
  const int c0 = blockIdx.x * 32, r0 = blockIdx.y * 32;
  const int tx = threadIdx.x & 31, ty = threadIdx.x >> 5;  // 32 x 8
#pragma unroll
  for (int i = 0; i < 4; i++) {
    int r = r0 + ty + i * 8;
    t[ty + i * 8][tx] = in[(size_t)r * C + c0 + tx];
  }
  __syncthreads();
#pragma unroll
  for (int i = 0; i < 4; i++) {
    int c = c0 + ty + i * 8;
    out[(size_t)c * R + r0 + tx] = f2bf(t[tx][ty + i * 8]);
  }
}

// ---------------- 256x256 bf16 GEMM for QKV: 2-tile lookahead + 1-phase register prefetch ----
// 8 waves (2M x 4N), BK=64, double-buffered swizzled LDS (128 KB).
// Register subtiles read ONE PHASE EARLY (reads overlap MFMA across phase boundary):
//   ph4(u-1): read a03(u), b01(u)   ph1(u): read b23(u)   ph2(u): read a47(u)
// LDS lifetimes: B(u) dead after ph1(u), A(u) dead after ph2(u) ->
//   stage B(u+2)@ph2(u), A(u+2)@ph3(u); vmcnt(8)@ph4(u) retires all of tile u+1.
__global__ __launch_bounds__(512, 2) void gemm256_qkv_k(const unsigned short* __restrict__ A,
                                                        const unsigned short* __restrict__ Bt,
                                                        unsigned short* __restrict__ Qg,
                                                        unsigned short* __restrict__ Kg,
                                                        unsigned short* __restrict__ Vg,
                                                        int K) {
  __shared__ __align__(16) unsigned short Asb[2][256 * 64];  // 64 KB
  __shared__ __align__(16) unsigned short Bsb[2][256 * 64];  // 64 KB
  const int tid = threadIdx.x;
  const int lane = tid & 63, wid = tid >> 6;
  const int wr = wid >> 2, wc = wid & 3;            // 2 x 4 wave grid
  const int cbase = lane & 15, rgrp = lane >> 4;
  const int bid = (int)blockIdx.x;
  const int id = (bid & 7) * 48 + (bid >> 3);       // XCD-bijective (384 = 8*48)
  const int nb = id >> 4, mb = id & 15;
  const size_t m0 = (size_t)mb * 256, n0 = (size_t)nb * 256;
  const int nkt = K >> 6;                           // 32 K-tiles (even)

#define STAGE_HALF(u_, half_) do {                                                      \
    const int uc_ = ((u_) < nkt ? (u_) : (nkt - 1));                                    \
    unsigned short* ldsb_ = (((half_) < 2) ? &Asb[(u_) & 1][0] : &Bsb[(u_) & 1][0])     \
                            + ((half_) & 1) * (128 * 64);                               \
    const unsigned short* gb_ = (((half_) < 2)                                          \
        ? A  + (m0 + (size_t)((half_) & 1) * 128) * (size_t)K                           \
        : Bt + (n0 + (size_t)((half_) & 1) * 128) * (size_t)K);                         \
    _Pragma("unroll")                                                                   \
    for (int ld_ = 0; ld_ < 2; ld_++) {                                                 \
      const int idx_ = ld_ * 512 + tid;                                                 \
      const int row_ = idx_ >> 3, seg_ = idx_ & 7;                                      \
      gload_lds16(gb_ + (size_t)row_ * K + uc_ * 64 +                                   \
                      (((seg_ * 16) ^ ((row_ & 7) << 4)) >> 1),                         \
                  ldsb_ + idx_ * 8);                                                    \
    } } while (0)

  const int axor = (cbase & 7) << 4;
  int a_off[2], b_off[2];
#pragma unroll
  for (int ks = 0; ks < 2; ks++) {
    a_off[ks] = ((wr * 128 + cbase) * 128 + ((ks * 64 + rgrp * 16) ^ axor)) >> 1;
    b_off[ks] = ((wc * 64 + cbase) * 128 + ((ks * 64 + rgrp * 16) ^ axor)) >> 1;
  }

#define RD_A03(dst_, p_) do { _Pragma("unroll")                                          \
    for (int mf_ = 0; mf_ < 4; mf_++) { _Pragma("unroll")                                \
      for (int ks_ = 0; ks_ < 2; ks_++)                                                  \
        dst_[mf_][ks_] = *(const bfx8*)((p_) + a_off[ks_] + mf_ * 1024); } } while (0)
#define RD_A47(dst_, p_) do { _Pragma("unroll")                                          \
    for (int mf_ = 0; mf_ < 4; mf_++) { _Pragma("unroll")                                \
      for (int ks_ = 0; ks_ < 2; ks_++)                                                  \
        dst_[mf_][ks_] = *(const bfx8*)((p_) + a_off[ks_] + (mf_ + 4) * 1024); } } while (0)
#define RD_B01(dst_, p_) do { _Pragma("unroll")                                          \
    for (int nf_ = 0; nf_ < 2; nf_++) { _Pragma("unroll")                                \
      for (int ks_ = 0; ks_ < 2; ks_++)                                                  \
        dst_[nf_][ks_] = *(const bfx8*)((p_) + b_off[ks_] + nf_ * 1024); } } while (0)
#define RD_B23(dst_, p_) do { _Pragma("unroll")                                          \
    for (int nf_ = 0; nf_ < 2; nf_++) { _Pragma("unroll")                                \
      for (int ks_ = 0; ks_ < 2; ks_++)                                                  \
        dst_[nf_][ks_] = *(const bfx8*)((p_) + b_off[ks_] + (nf_ + 2) * 1024); } } while (0)

#define MFMA_Q(mo_, no_, AF_, BF_) do {                                                  \
    __builtin_amdgcn_s_setprio(1);                                                      \
    _Pragma("unroll")                                                                    \
    for (int mf_ = 0; mf_ < 4; mf_++) { _Pragma("unroll")                                \
      for (int nf_ = 0; nf_ < 2; nf_++) { _Pragma("unroll")                              \
        for (int ks_ = 0; ks_ < 2; ks_++)                                                \
          acc[mf_ + (mo_)][nf_ + (no_)] = __builtin_amdgcn_mfma_f32_16x16x32_bf16(       \
              AF_[mf_][ks_], BF_[nf_][ks_], acc[mf_ + (mo_)][nf_ + (no_)], 0, 0, 0); } } \
    __builtin_amdgcn_s_setprio(0); } while (0)

  f32x4 acc[8][4];
  const f32x4 z = {0.f, 0.f, 0.f, 0.f};
#pragma unroll
  for (int mf = 0; mf < 8; mf++)
#pragma unroll
    for (int nf = 0; nf < 4; nf++) acc[mf][nf] = z;

  // prologue: stage tiles 0,1 fully; tile0 resident; prefetch tile0's Q1 fragments
  STAGE_HALF(0, 2); STAGE_HALF(0, 3); STAGE_HALF(0, 0); STAGE_HALF(0, 1);
  STAGE_HALF(1, 2); STAGE_HALF(1, 3); STAGE_HALF(1, 0); STAGE_HALF(1, 1);
  VMCNT8();
  BARS();
  bfx8 a03A[4][2], b01A[2][2], a03B[4][2], b01B[2][2];
  RD_A03(a03A, &Asb[0][0]);
  RD_B01(b01A, &Bsb[0][0]);

#define TILE_BODY(u_, A03_, B01_, NA03_, NB01_) do {                                     \
    const unsigned short* As_  = &Asb[(u_) & 1][0];                                      \
    const unsigned short* Bs_  = &Bsb[(u_) & 1][0];                                      \
    const unsigned short* Asn_ = &Asb[((u_) + 1) & 1][0];                                \
    const unsigned short* Bsn_ = &Bsb[((u_) + 1) & 1][0];                                \
    bfx8 a47[4][2], b23[2][2];                                                           \
    /* ph1: prefetch b23(u); MFMA Q1 (uses A03_,B01_ read last phase) */                 \
    RD_B23(b23, Bs_);                                                                    \
    BARS();                                                                              \
    MFMA_Q(0, 0, A03_, B01_);                                                            \
    BARS();   /* B(u) dead for all waves */                                              \
    /* ph2: prefetch a47(u); stage B(u+2) into dead region; MFMA Q2 */                   \
    RD_A47(a47, As_);                                                                    \
    STAGE_HALF((u_) + 2, 2); STAGE_HALF((u_) + 2, 3);                                    \
    BARS();                                                                              \
    MFMA_Q(0, 2, A03_, b23);                                                             \
    BARS();   /* A(u) dead for all waves */                                              \
    /* ph3: stage A(u+2) into dead region; MFMA Q3 */                                    \
    STAGE_HALF((u_) + 2, 0); STAGE_HALF((u_) + 2, 1);                                    \
    BARS();                                                                              \
    MFMA_Q(4, 0, a47, B01_);                                                             \
    BARS();                                                                              \
    /* ph4: vmcnt(8) -> tile u+1 resident (8 newest = u+2's loads); barrier makes it */  \
    /* block-wide; prefetch next tile's Q1 fragments; MFMA Q4 */                         \
    VMCNT8();                                                                            \
    BARS();                                                                              \
    RD_A03(NA03_, Asn_);                                                                 \
    RD_B01(NB01_, Bsn_);                                                                 \
    MFMA_Q(4, 2, a47, b23);                                                              \
    BARS();                                                                              \
  } while (0)

#pragma unroll 1
  for (int u = 0; u < nkt; u += 2) {
    TILE_BODY(u,     a03A, b01A, a03B, b01B);
    TILE_BODY(u + 1, a03B, b01B, a03A, b01A);
  }
#undef TILE_BODY
#undef STAGE_HALF

  // ---- split epilogue: n -> (head, q/k/v, d) ----
#pragma unroll
  for (int mf = 0; mf < 8; mf++)
#pragma unroll
    for (int nf = 0; nf < 4; nf++) {
      const int nn = (int)n0 + wc * 64 + nf * 16;
      const int h = nn / 384, tt = (nn >> 7) % 3;
      const int d = (nn & 127) + cbase;
      const int row0 = (int)m0 + wr * 128 + mf * 16 + rgrp * 4;
      const int bb = row0 >> 11;
      const int s0 = row0 & 2047;
      if (tt == 2) {
        ushort4 v;
        v.x = f2bf(acc[mf][nf][0]); v.y = f2bf(acc[mf][nf][1]);
        v.z = f2bf(acc[mf][nf][2]); v.w = f2bf(acc[mf][nf][3]);
        *(ushort4*)(Vg + ((size_t)(bb * HD + h) * DH + d) * SS + s0) = v;
      } else {
        unsigned short* dst = (tt == 0 ? Qg : Kg);
#pragma unroll
        for (int r = 0; r < 4; r++)
          dst[((size_t)(bb * HD + h) * SS + s0 + r) * DH + d] = f2bf(acc[mf][nf][r]);
      }
    }
}

// ---------------- 128x128 bf16 GEMM for out-proj: C f32 = A * Bt^T ----------------
__global__ __launch_bounds__(256) void gemm_out_k(const unsigned short* __restrict__ A,
                                                  const unsigned short* __restrict__ Bt,
                                                  float* __restrict__ C, int K, int ldc) {
  __shared__ __align__(16) unsigned short As[128 * 32];
  __shared__ __align__(16) unsigned short Bs[128 * 32];
  const int tid = threadIdx.x;
  const int lane = tid & 63, wid = tid >> 6;
  const int wr = wid >> 1, wc = wid & 1;
  const int cbase = lane & 15, rgrp = lane >> 4;
  const size_t m0 = (size_t)blockIdx.y * 128, n0 = (size_t)blockIdx.x * 128;

  f32x4 acc[4][4];
  const f32x4 z = {0.f, 0.f, 0.f, 0.f};
#pragma unroll
  for (int mf = 0; mf < 4; mf++)
#pragma unroll
    for (int nf = 0; nf < 4; nf++) acc[mf][nf] = z;

  const int nkt = K >> 5;
  for (int kt = 0; kt < nkt; ++kt) {
#pragma unroll
    for (int i = 0; i < 2; i++) {
      int idx = i * 256 + tid;
      int row = idx >> 2, cb = idx & 3;
      gload_lds16(A + (m0 + row) * K + (kt * 32 + cb * 8), As + idx * 8);
      gload_lds16(Bt + (n0 + row) * K + (kt * 32 + cb * 8), Bs + idx * 8);
    }
    __syncthreads();
    bfx8 af[4], bfr[4];
#pragma unroll
    for (int mf = 0; mf < 4; mf++)
      af[mf] = *(const bfx8*)(As + (wr * 64 + mf * 16 + cbase) * 32 + rgrp * 8);
#pragma unroll
    for (int nf = 0; nf < 4; nf++)
      bfr[nf] = *(const bfx8*)(Bs + (wc * 64 + nf * 16 + cbase) * 32 + rgrp * 8);
#pragma unroll
    for (int mf = 0; mf < 4; mf++)
#pragma unroll
      for (int nf = 0; nf < 4; nf++)
        acc[mf][nf] = __builtin_amdgcn_mfma_f32_16x16x32_bf16(af[mf], bfr[nf], acc[mf][nf], 0, 0, 0);
    __syncthreads();
  }

#pragma unroll
  for (int mf = 0; mf < 4; mf++)
#pragma unroll
    for (int nf = 0; nf < 4; nf++)
#pragma unroll
      for (int r = 0; r < 4; r++) {
        size_t row = m0 + wr * 64 + mf * 16 + rgrp * 4 + r;
        size_t col = n0 + wc * 64 + nf * 16 + cbase;
        C[row * ldc + col] = acc[mf][nf][r];
      }
}

// ---------------- flash attention (bf16, swapped-operand in-register softmax) ----------------
__global__ __launch_bounds__(256) void attn_fwd_k(const unsigned short* __restrict__ Qg,
                                                  const unsigned short* __restrict__ Kg,
                                                  const unsigned short* __restrict__ Vg,
                                                  unsigned short* __restrict__ ao) {
  __shared__ __align__(16) unsigned short Klds[2][64 * 128];   // 2 x 16 KB
  __shared__ __align__(16) unsigned short Vt[2][128 * 64];     // 2 x 16 KB
  __shared__ __align__(16) unsigned short Plds[4][16 * 64];    // 8 KB per-wave P rows
  const int tid = threadIdx.x;
  const int lane = tid & 63, wid = tid >> 6;
  const int cbase = lane & 15, rgrp = lane >> 4;
  const int cx = (cbase & 7) << 4;

  const int bid = (int)blockIdx.x;
  const int bh = (bid & 7) * 4 + ((bid >> 3) & 3);
  const int qt = 31 - (bid >> 5);
  const int b = bh >> 4, h = bh & 15;
  const int qbase = qt * 64;

  const unsigned short* qp0 = Qg + (size_t)(b * HD + h) * SS * DH;
  const unsigned short* kp  = Kg + (size_t)(b * HD + h) * SS * DH;
  const unsigned short* vp  = Vg + (size_t)(b * HD + h) * DH * SS;
  const float scale = 0.08838834764831845f;
  const f32x4 z = {0.f, 0.f, 0.f, 0.f};
  const int qi = qbase + wid * 16 + cbase;

  bfx8 qf[4];
  {
    const unsigned short* qp = qp0 + (size_t)qi * DH;
#pragma unroll
    for (int ks = 0; ks < 4; ks++) qf[ks] = *(const bfx8*)(qp + ks * 32 + rgrp * 8);
  }

  float m_run = -1e30f, l_run = 0.f;
  f32x4 o[8];
#pragma unroll
  for (int mb = 0; mb < 8; mb++) o[mb] = z;

#define STAGE_T(t_, s_) do {                                                        \
    const int kvb_ = (t_) * 64;                                                     \
    _Pragma("unroll")                                                               \
    for (int i_ = 0; i_ < 4; i_++) {                                                \
      int idx_ = i_ * 256 + tid;                                                    \
      int r_ = idx_ >> 4, bo_ = (idx_ & 15) * 16;                                   \
      gload_lds16(kp + (size_t)(kvb_ + r_) * DH + ((bo_ ^ ((r_ & 7) << 4)) >> 1),   \
                  &Klds[s_][idx_ * 8]);                                             \
    }                                                                               \
    _Pragma("unroll")                                                               \
    for (int i_ = 0; i_ < 4; i_++) {                                                \
      int idx_ = i_ * 256 + tid;                                                    \
      int d_ = idx_ >> 3, bo_ = (idx_ & 7) * 16;                                    \
      gload_lds16(vp + (size_t)d_ * SS + kvb_ + ((bo_ ^ ((d_ & 7) << 4)) >> 1),     \
                  &Vt[s_][idx_ * 8]);                                               \
    } } while (0)

  const int ntiles = qt + 1;
  STAGE_T(0, 0);
  __syncthreads();

  for (int t = 0; t < ntiles; ++t) {
    const int sel = t & 1;
    if (t + 1 < ntiles) STAGE_T(t + 1, sel ^ 1);
    const unsigned short* Ks_ = &Klds[sel][0];
    const unsigned short* Vs_ = &Vt[sel][0];
    const int kvb = t * 64;

    f32x4 s[4];
#pragma unroll
    for (int mf = 0; mf < 4; mf++) s[mf] = z;
#pragma unroll
    for (int mf = 0; mf < 4; mf++)
#pragma unroll
      for (int ks = 0; ks < 4; ks++) {
        bfx8 kf = *(const bfx8*)(Ks_ + (((mf * 16 + cbase) * 256 + ((ks * 64 + rgrp * 16) ^ cx)) >> 1));
        s[mf] = __builtin_amdgcn_mfma_f32_16x16x32_bf16(kf, qf[ks], s[mf], 0, 0, 0);
      }

    float sv[4][4];
    const bool diag = (t == ntiles - 1);
#pragma unroll
    for (int mf = 0; mf < 4; mf++)
#pragma unroll
      for (int r = 0; r < 4; r++) {
        float v = s[mf][r] * scale;
        if (diag && (kvb + mf * 16 + rgrp * 4 + r > qi)) v = -1e30f;
        sv[mf][r] = v;
      }
    float tm = sv[0][0];
#pragma unroll
    for (int mf = 0; mf < 4; mf++)
#pragma unroll
      for (int r = 0; r < 4; r++) tm = fmaxf(tm, sv[mf][r]);
    tm = fmaxf(tm, __shfl_xor(tm, 16));
    tm = fmaxf(tm, __shfl_xor(tm, 32));
    const float mnew = fmaxf(m_run, tm);
    float p[4][4];
    float rs = 0.f;
#pragma unroll
    for (int mf = 0; mf < 4; mf++)
#pragma unroll
      for (int r = 0; r < 4; r++) { p[mf][r] = __expf(sv[mf][r] - mnew); rs += p[mf][r]; }
    rs += __shfl_xor(rs, 16);
    rs += __shfl_xor(rs, 32);
    const float alpha = __expf(m_run - mnew);
    l_run = l_run * alpha + rs;
    m_run = mnew;
#pragma unroll
    for (int mb = 0; mb < 8; mb++)
#pragma unroll
      for (int r = 0; r < 4; r++) o[mb][r] *= alpha;

#pragma unroll
    for (int mf = 0; mf < 4; mf++)
#pragma unroll
      for (int rr = 0; rr < 2; rr++) {
        unsigned int pp = (unsigned int)f2bf(p[mf][2 * rr]) |
                          ((unsigned int)f2bf(p[mf][2 * rr + 1]) << 16);
        *(unsigned int*)((char*)&Plds[wid][0] +
                         (cbase * 128 + ((mf * 32 + rgrp * 8 + rr * 4) ^ cx))) = pp;
      }
    bfx8 pf[2];
#pragma unroll
    for (int k2 = 0; k2 < 2; k2++)
      pf[k2] = *(const bfx8*)((const char*)&Plds[wid][0] +
                              (cbase * 128 + ((k2 * 64 + rgrp * 16) ^ cx)));

#pragma unroll
    for (int mb = 0; mb < 8; mb++)
#pragma unroll
      for (int k2 = 0; k2 < 2; k2++) {
        bfx8 vf = *(const bfx8*)(Vs_ + (((mb * 16 + cbase) * 128 + ((k2 * 64 + rgrp * 16) ^ cx)) >> 1));
        o[mb] = __builtin_amdgcn_mfma_f32_16x16x32_bf16(vf, pf[k2], o[mb], 0, 0, 0);
      }
    __syncthreads();
  }
#undef STAGE_T

  const float rinv = 1.0f / l_run;
  unsigned short* aop = ao + ((size_t)(b * SS + qi)) * DM + h * DH + rgrp * 4;
#pragma unroll
  for (int mb = 0; mb < 8; mb++) {
    ushort4 v;
    v.x = f2bf(o[mb][0] * rinv); v.y = f2bf(o[mb][1] * rinv);
    v.z = f2bf(o[mb][2] * rinv); v.w = f2bf(o[mb][3] * rinv);
    *(ushort4*)(aop + mb * 16) = v;
  }
}

extern "C" void kernel_launch(void* const* d_in, const int* in_sizes, int n_in,
                              void* d_out, int out_size, void* d_ws, size_t ws_size,
                              hipStream_t stream) {
  (void)in_sizes; (void)n_in; (void)out_size; (void)ws_size;
  const float* x     = (const float*)d_in[0];
  const float* w_in  = (const float*)d_in[1];
  const float* w_out = (const float*)d_in[2];
  float* out = (float*)d_out;

  char* ws = (char*)d_ws;
  unsigned short* Xb  = (unsigned short*)(ws);                     // 16 MB  [4096][2048]
  unsigned short* Wit = (unsigned short*)(ws + (16ull << 20));     // 24 MB  [6144][2048]
  unsigned short* Wot = (unsigned short*)(ws + (40ull << 20));     //  8 MB  [2048][2048]
  unsigned short* Qg  = (unsigned short*)(ws + (48ull << 20));     // 16 MB  [b][h][s][d]
  unsigned short* Kg  = (unsigned short*)(ws + (64ull << 20));     // 16 MB  [b][h][s][d]
  unsigned short* Vg  = (unsigned short*)(ws + (80ull << 20));     // 16 MB  [b][h][d][s]
  unsigned short* AO  = (unsigned short*)(ws + (96ull << 20));     // 16 MB  [4096][2048]

  f32_to_bf16_k<<<MTOT * DM / 4 / 256, 256, 0, stream>>>(x, Xb, MTOT * DM / 4);
  transpose_f32_bf16_k<<<dim3(NQKV / 32, DM / 32), 256, 0, stream>>>(w_in, Wit, DM, NQKV);
  transpose_f32_bf16_k<<<dim3(DM / 32, DM / 32), 256, 0, stream>>>(w_out, Wot, DM, DM);
  gemm256_qkv_k<<<384, 512, 0, stream>>>(Xb, Wit, Qg, Kg, Vg, DM);
  attn_fwd_k<<<1024, 256, 0, stream>>>(Qg, Kg, Vg, AO);
  gemm_out_k<<<dim3(DM / 128, MTOT / 128), 256, 0, stream>>>(AO, Wot, out, DM, DM);
}

// Round 14
// 253.808 us; speedup vs baseline: 1.4238x; 1.0759x over previous
//
#include <hip/hip_runtime.h>

// Problem constants
#define HD    16
#define DH    128
#define BB    2
#define SS    2048
#define DM    2048
#define NQKV  6144   // 3*HD*DH
#define MTOT  4096   // BB*SS

typedef short   bfx8  __attribute__((ext_vector_type(8)));   // 8 bf16 (4 VGPRs)
typedef float   f32x4 __attribute__((ext_vector_type(4)));

__device__ __forceinline__ unsigned short f2bf(float f) {
  union { float f; unsigned int u; } c; c.f = f;
  unsigned int u = c.u + 0x7FFFu + ((c.u >> 16) & 1u);
  return (unsigned short)(u >> 16);
}

__device__ __forceinline__ void gload_lds16(const unsigned short* g, unsigned short* l) {
  __builtin_amdgcn_global_load_lds(
      (const __attribute__((address_space(1))) unsigned int*)g,
      (__attribute__((address_space(3))) unsigned int*)l, 16, 0, 0);
}

// raw barrier fenced against compiler reordering (no vmcnt/lgkmcnt drain)
#define BARS() do { __builtin_amdgcn_sched_barrier(0); __builtin_amdgcn_s_barrier(); \
                    __builtin_amdgcn_sched_barrier(0); } while (0)
#define VMCNT7() do { asm volatile("s_waitcnt vmcnt(7)" ::: "memory"); \
                      __builtin_amdgcn_sched_barrier(0); } while (0)

// ---------------- f32 -> bf16 cast ----------------
__global__ __launch_bounds__(256) void f32_to_bf16_k(const float* __restrict__ in,
                                                     unsigned short* __restrict__ out, int n4) {
  int i = (blockIdx.x * 256 + threadIdx.x);
  if (i >= n4) return;
  const float4 v = *(const float4*)(in + (size_t)i * 4);
  ushort4 o;
  o.x = f2bf(v.x); o.y = f2bf(v.y); o.z = f2bf(v.z); o.w = f2bf(v.w);
  *(ushort4*)(out + (size_t)i * 4) = o;
}

// ---------------- f32 [R][C] -> bf16 [C][R] transpose ----------------
__global__ __launch_bounds__(256) void transpose_f32_bf16_k(const float* __restrict__ in,
                                                            unsigned short* __restrict__ out,
                                                            int R, int C) {
  __shared__ float t[32][33];
  const int c0 = blockIdx.x * 32, r0 = blockIdx.y * 32;
  const int tx = threadIdx.x & 31, ty = threadIdx.x >> 5;  // 32 x 8
#pragma unroll
  for (int i = 0; i < 4; i++) {
    int r = r0 + ty + i * 8;
    t[ty + i * 8][tx] = in[(size_t)r * C + c0 + tx];
  }
  __syncthreads();
#pragma unroll
  for (int i = 0; i < 4; i++) {
    int c = c0 + ty + i * 8;
    out[(size_t)c * R + r0 + tx] = f2bf(t[tx][ty + i * 8]);
  }
}

// ---------------- 256x192 bf16 GEMM for QKV: exact-grid (512 = 2 rounds), 3-phase pipeline ----
// 8 waves (2M x 4N), wave tile 128x48, BK=64, double-buffered swizzled LDS (112 KB).
// 3 phases/tile, 16 MFMA each, ONE barrier per phase. Register prefetch one phase early:
//   ph3(u-1): a03(u), b01(u);  ph1(u): a47(u);  ph2(u): b2(u).
// Staging by 64-row groups (1 gload/thread), into regions proven dead:
//   ph1: A-g0,g2(u+2)  ph2: A-g1,g3(u+2)  ph3: B-g0,g1,g2(u+2); vmcnt(7) retires tile u+1.
__global__ __launch_bounds__(512, 2) void gemm256_qkv_k(const unsigned short* __restrict__ A,
                                                        const unsigned short* __restrict__ Bt,
                                                        unsigned short* __restrict__ Qg,
                                                        unsigned short* __restrict__ Kg,
                                                        unsigned short* __restrict__ Vg,
                                                        int K) {
  __shared__ __align__(16) unsigned short Asb[2][256 * 64];  // 64 KB
  __shared__ __align__(16) unsigned short Bsb[2][192 * 64];  // 48 KB
  const int tid = threadIdx.x;
  const int lane = tid & 63, wid = tid >> 6;
  const int wr = wid >> 2, wc = wid & 3;            // 2 x 4 wave grid
  const int cbase = lane & 15, rgrp = lane >> 4;
  const int bid = (int)blockIdx.x;
  const int id = (bid & 7) * 64 + (bid >> 3);       // XCD-bijective (512 = 8*64)
  const int nb = id >> 4, mb = id & 15;             // XCD owns 4 n-panels (3 MB B, L2-fit)
  const size_t m0 = (size_t)mb * 256, n0 = (size_t)nb * 192;
  const int nkt = K >> 6;                           // 32 K-tiles (even)

  // stage one 64-row group (8 KB, 1 gload/thread). g: A in 0..3, B in 0..2.
#define STAGE_A64(u_, g_) do {                                                          \
    const int uc_ = ((u_) < nkt ? (u_) : (nkt - 1));                                    \
    const int r_ = tid >> 3, s_ = tid & 7;                                              \
    gload_lds16(A + (m0 + (g_) * 64 + r_) * (size_t)K + uc_ * 64 +                      \
                    (((s_ * 16) ^ ((r_ & 7) << 4)) >> 1),                               \
                &Asb[(u_) & 1][(g_) * 4096] + tid * 8); } while (0)
#define STAGE_B64(u_, g_) do {                                                          \
    const int uc_ = ((u_) < nkt ? (u_) : (nkt - 1));                                    \
    const int r_ = tid >> 3, s_ = tid & 7;                                              \
    gload_lds16(Bt + (n0 + (g_) * 64 + r_) * (size_t)K + uc_ * 64 +                     \
                    (((s_ * 16) ^ ((r_ & 7) << 4)) >> 1),                               \
                &Bsb[(u_) & 1][(g_) * 4096] + tid * 8); } while (0)

  const int axor = (cbase & 7) << 4;
  int a_off[2], b_off[2];
#pragma unroll
  for (int ks = 0; ks < 2; ks++) {
    a_off[ks] = ((wr * 128 + cbase) * 128 + ((ks * 64 + rgrp * 16) ^ axor)) >> 1;
    b_off[ks] = ((wc * 48 + cbase) * 128 + ((ks * 64 + rgrp * 16) ^ axor)) >> 1;
  }

#define RD_A03(dst_, p_) do { _Pragma("unroll")                                          \
    for (int mf_ = 0; mf_ < 4; mf_++) { _Pragma("unroll")                                \
      for (int ks_ = 0; ks_ < 2; ks_++)                                                  \
        dst_[mf_][ks_] = *(const bfx8*)((p_) + a_off[ks_] + mf_ * 1024); } } while (0)
#define RD_A47(dst_, p_) do { _Pragma("unroll")                                          \
    for (int mf_ = 0; mf_ < 4; mf_++) { _Pragma("unroll")                                \
      for (int ks_ = 0; ks_ < 2; ks_++)                                                  \
        dst_[mf_][ks_] = *(const bfx8*)((p_) + a_off[ks_] + (mf_ + 4) * 1024); } } while (0)
#define RD_B01(dst_, p_) do { _Pragma("unroll")                                          \
    for (int nf_ = 0; nf_ < 2; nf_++) { _Pragma("unroll")                                \
      for (int ks_ = 0; ks_ < 2; ks_++)                                                  \
        dst_[nf_][ks_] = *(const bfx8*)((p_) + b_off[ks_] + nf_ * 1024); } } while (0)
#define RD_B2(dst_, p_) do { _Pragma("unroll")                                           \
    for (int ks_ = 0; ks_ < 2; ks_++)                                                    \
      dst_[0][ks_] = *(const bfx8*)((p_) + b_off[ks_] + 2 * 1024); } while (0)

#define MFMA_2N(mo_, AF_, BF_) do {                                                      \
    __builtin_amdgcn_s_setprio(1);                                                      \
    _Pragma("unroll")                                                                    \
    for (int mf_ = 0; mf_ < 4; mf_++) { _Pragma("unroll")                                \
      for (int nf_ = 0; nf_ < 2; nf_++) { _Pragma("unroll")                              \
        for (int ks_ = 0; ks_ < 2; ks_++)                                                \
          acc[mf_ + (mo_)][nf_] = __builtin_amdgcn_mfma_f32_16x16x32_bf16(               \
              AF_[mf_][ks_], BF_[nf_][ks_], acc[mf_ + (mo_)][nf_], 0, 0, 0); } }         \
    __builtin_amdgcn_s_setprio(0); } while (0)

  f32x4 acc[8][3];
  const f32x4 z = {0.f, 0.f, 0.f, 0.f};
#pragma unroll
  for (int mf = 0; mf < 8; mf++)
#pragma unroll
    for (int nf = 0; nf < 3; nf++) acc[mf][nf] = z;

  // prologue: stage tiles 0 and 1 fully (14 loads); vmcnt(7) -> tile 0 landed
  STAGE_A64(0, 0); STAGE_A64(0, 1); STAGE_A64(0, 2); STAGE_A64(0, 3);
  STAGE_B64(0, 0); STAGE_B64(0, 1); STAGE_B64(0, 2);
  STAGE_A64(1, 0); STAGE_A64(1, 1); STAGE_A64(1, 2); STAGE_A64(1, 3);
  STAGE_B64(1, 0); STAGE_B64(1, 1); STAGE_B64(1, 2);
  VMCNT7();
  BARS();
  bfx8 a03A[4][2], b01A[2][2], a03B[4][2], b01B[2][2];
  RD_A03(a03A, &Asb[0][0]);
  RD_B01(b01A, &Bsb[0][0]);

#define TILE_BODY(u_, A03c, B01c, A03n, B01n) do {                                       \
    const unsigned short* As_  = &Asb[(u_) & 1][0];                                      \
    const unsigned short* Bs_  = &Bsb[(u_) & 1][0];                                      \
    const unsigned short* Asn_ = &Asb[((u_) + 1) & 1][0];                                \
    const unsigned short* Bsn_ = &Bsb[((u_) + 1) & 1][0];                                \
    bfx8 a47[4][2], b2[1][2];                                                            \
    /* ph1: read a47(u); stage A-g0,g2(u+2) (dead since a03 read @ph3(u-1)) */           \
    RD_A47(a47, As_);                                                                    \
    STAGE_A64((u_) + 2, 0); STAGE_A64((u_) + 2, 2);                                      \
    BARS();                                                                              \
    MFMA_2N(0, A03c, B01c);                                                              \
    /* ph2: read b2(u); stage A-g1,g3(u+2) (dead after a47 read @ph1) */                 \
    RD_B2(b2, Bs_);                                                                      \
    STAGE_A64((u_) + 2, 1); STAGE_A64((u_) + 2, 3);                                      \
    BARS();                                                                              \
    MFMA_2N(4, a47, B01c);                                                               \
    /* ph3: stage B(u+2) (dead after b01@ph3(u-1), b2@ph2); vmcnt(7) -> u+1 resident; */ \
    /* prefetch next tile's a03/b01; MFMA column nf=2 */                                 \
    STAGE_B64((u_) + 2, 0); STAGE_B64((u_) + 2, 1); STAGE_B64((u_) + 2, 2);              \
    VMCNT7();                                                                            \
    BARS();                                                                              \
    RD_A03(A03n, Asn_);                                                                  \
    RD_B01(B01n, Bsn_);                                                                  \
    __builtin_amdgcn_s_setprio(1);                                                      \
    _Pragma("unroll")                                                                    \
    for (int mf_ = 0; mf_ < 4; mf_++) { _Pragma("unroll")                                \
      for (int ks_ = 0; ks_ < 2; ks_++) {                                                \
        acc[mf_][2] = __builtin_amdgcn_mfma_f32_16x16x32_bf16(                           \
            A03c[mf_][ks_], b2[0][ks_], acc[mf_][2], 0, 0, 0);                           \
        acc[mf_ + 4][2] = __builtin_amdgcn_mfma_f32_16x16x32_bf16(                       \
            a47[mf_][ks_], b2[0][ks_], acc[mf_ + 4][2], 0, 0, 0);                        \
      } }                                                                                \
    __builtin_amdgcn_s_setprio(0);                                                      \
    BARS();                                                                              \
  } while (0)

#pragma unroll 1
  for (int u = 0; u < nkt; u += 2) {
    TILE_BODY(u,     a03A, b01A, a03B, b01B);
    TILE_BODY(u + 1, a03B, b01B, a03A, b01A);
  }
#undef TILE_BODY
#undef STAGE_A64
#undef STAGE_B64

  // ---- split epilogue: n -> (head, q/k/v, d); each 16-wide frag within one class ----
#pragma unroll
  for (int mf = 0; mf < 8; mf++)
#pragma unroll
    for (int nf = 0; nf < 3; nf++) {
      const int nn = (int)n0 + wc * 48 + nf * 16;
      const int h = nn / 384, tt = (nn >> 7) % 3;
      const int d = (nn & 127) + cbase;
      const int row0 = (int)m0 + wr * 128 + mf * 16 + rgrp * 4;
      const int bb = row0 >> 11;
      const int s0 = row0 & 2047;
      if (tt == 2) {
        ushort4 v;
        v.x = f2bf(acc[mf][nf][0]); v.y = f2bf(acc[mf][nf][1]);
        v.z = f2bf(acc[mf][nf][2]); v.w = f2bf(acc[mf][nf][3]);
        *(ushort4*)(Vg + ((size_t)(bb * HD + h) * DH + d) * SS + s0) = v;
      } else {
        unsigned short* dst = (tt == 0 ? Qg : Kg);
#pragma unroll
        for (int r = 0; r < 4; r++)
          dst[((size_t)(bb * HD + h) * SS + s0 + r) * DH + d] = f2bf(acc[mf][nf][r]);
      }
    }
}

// ---------------- 128x128 bf16 GEMM for out-proj: C f32 = A * Bt^T ----------------
__global__ __launch_bounds__(256) void gemm_out_k(const unsigned short* __restrict__ A,
                                                  const unsigned short* __restrict__ Bt,
                                                  float* __restrict__ C, int K, int ldc) {
  __shared__ __align__(16) unsigned short As[128 * 32];
  __shared__ __align__(16) unsigned short Bs[128 * 32];
  const int tid = threadIdx.x;
  const int lane = tid & 63, wid = tid >> 6;
  const int wr = wid >> 1, wc = wid & 1;
  const int cbase = lane & 15, rgrp = lane >> 4;
  const size_t m0 = (size_t)blockIdx.y * 128, n0 = (size_t)blockIdx.x * 128;

  f32x4 acc[4][4];
  const f32x4 z = {0.f, 0.f, 0.f, 0.f};
#pragma unroll
  for (int mf = 0; mf < 4; mf++)
#pragma unroll
    for (int nf = 0; nf < 4; nf++) acc[mf][nf] = z;

  const int nkt = K >> 5;
  for (int kt = 0; kt < nkt; ++kt) {
#pragma unroll
    for (int i = 0; i < 2; i++) {
      int idx = i * 256 + tid;
      int row = idx >> 2, cb = idx & 3;
      gload_lds16(A + (m0 + row) * K + (kt * 32 + cb * 8), As + idx * 8);
      gload_lds16(Bt + (n0 + row) * K + (kt * 32 + cb * 8), Bs + idx * 8);
    }
    __syncthreads();
    bfx8 af[4], bfr[4];
#pragma unroll
    for (int mf = 0; mf < 4; mf++)
      af[mf] = *(const bfx8*)(As + (wr * 64 + mf * 16 + cbase) * 32 + rgrp * 8);
#pragma unroll
    for (int nf = 0; nf < 4; nf++)
      bfr[nf] = *(const bfx8*)(Bs + (wc * 64 + nf * 16 + cbase) * 32 + rgrp * 8);
#pragma unroll
    for (int mf = 0; mf < 4; mf++)
#pragma unroll
      for (int nf = 0; nf < 4; nf++)
        acc[mf][nf] = __builtin_amdgcn_mfma_f32_16x16x32_bf16(af[mf], bfr[nf], acc[mf][nf], 0, 0, 0);
    __syncthreads();
  }

#pragma unroll
  for (int mf = 0; mf < 4; mf++)
#pragma unroll
    for (int nf = 0; nf < 4; nf++)
#pragma unroll
      for (int r = 0; r < 4; r++) {
        size_t row = m0 + wr * 64 + mf * 16 + rgrp * 4 + r;
        size_t col = n0 + wc * 64 + nf * 16 + cbase;
        C[row * ldc + col] = acc[mf][nf][r];
      }
}

// ---------------- flash attention (bf16, swapped-operand in-register softmax) ----------------
__global__ __launch_bounds__(256) void attn_fwd_k(const unsigned short* __restrict__ Qg,
                                                  const unsigned short* __restrict__ Kg,
                                                  const unsigned short* __restrict__ Vg,
                                                  unsigned short* __restrict__ ao) {
  __shared__ __align__(16) unsigned short Klds[2][64 * 128];   // 2 x 16 KB
  __shared__ __align__(16) unsigned short Vt[2][128 * 64];     // 2 x 16 KB
  __shared__ __align__(16) unsigned short Plds[4][16 * 64];    // 8 KB per-wave P rows
  const int tid = threadIdx.x;
  const int lane = tid & 63, wid = tid >> 6;
  const int cbase = lane & 15, rgrp = lane >> 4;
  const int cx = (cbase & 7) << 4;

  const int bid = (int)blockIdx.x;
  const int bh = (bid & 7) * 4 + ((bid >> 3) & 3);
  const int qt = 31 - (bid >> 5);
  const int b = bh >> 4, h = bh & 15;
  const int qbase = qt * 64;

  const unsigned short* qp0 = Qg + (size_t)(b * HD + h) * SS * DH;
  const unsigned short* kp  = Kg + (size_t)(b * HD + h) * SS * DH;
  const unsigned short* vp  = Vg + (size_t)(b * HD + h) * DH * SS;
  const float scale = 0.08838834764831845f;
  const f32x4 z = {0.f, 0.f, 0.f, 0.f};
  const int qi = qbase + wid * 16 + cbase;

  bfx8 qf[4];
  {
    const unsigned short* qp = qp0 + (size_t)qi * DH;
#pragma unroll
    for (int ks = 0; ks < 4; ks++) qf[ks] = *(const bfx8*)(qp + ks * 32 + rgrp * 8);
  }

  float m_run = -1e30f, l_run = 0.f;
  f32x4 o[8];
#pragma unroll
  for (int mb = 0; mb < 8; mb++) o[mb] = z;

#define STAGE_T(t_, s_) do {                                                        \
    const int kvb_ = (t_) * 64;                                                     \
    _Pragma("unroll")                                                               \
    for (int i_ = 0; i_ < 4; i_++) {                                                \
      int idx_ = i_ * 256 + tid;                                                    \
      int r_ = idx_ >> 4, bo_ = (idx_ & 15) * 16;                                   \
      gload_lds16(kp + (size_t)(kvb_ + r_) * DH + ((bo_ ^ ((r_ & 7) << 4)) >> 1),   \
                  &Klds[s_][idx_ * 8]);                                             \
    }                                                                               \
    _Pragma("unroll")                                                               \
    for (int i_ = 0; i_ < 4; i_++) {                                                \
      int idx_ = i_ * 256 + tid;                                                    \
      int d_ = idx_ >> 3, bo_ = (idx_ & 7) * 16;                                    \
      gload_lds16(vp + (size_t)d_ * SS + kvb_ + ((bo_ ^ ((d_ & 7) << 4)) >> 1),     \
                  &Vt[s_][idx_ * 8]);                                               \
    } } while (0)

  const int ntiles = qt + 1;
  STAGE_T(0, 0);
  __syncthreads();

  for (int t = 0; t < ntiles; ++t) {
    const int sel = t & 1;
    if (t + 1 < ntiles) STAGE_T(t + 1, sel ^ 1);
    const unsigned short* Ks_ = &Klds[sel][0];
    const unsigned short* Vs_ = &Vt[sel][0];
    const int kvb = t * 64;

    f32x4 s[4];
#pragma unroll
    for (int mf = 0; mf < 4; mf++) s[mf] = z;
#pragma unroll
    for (int mf = 0; mf < 4; mf++)
#pragma unroll
      for (int ks = 0; ks < 4; ks++) {
        bfx8 kf = *(const bfx8*)(Ks_ + (((mf * 16 + cbase) * 256 + ((ks * 64 + rgrp * 16) ^ cx)) >> 1));
        s[mf] = __builtin_amdgcn_mfma_f32_16x16x32_bf16(kf, qf[ks], s[mf], 0, 0, 0);
      }

    float sv[4][4];
    const bool diag = (t == ntiles - 1);
#pragma unroll
    for (int mf = 0; mf < 4; mf++)
#pragma unroll
      for (int r = 0; r < 4; r++) {
        float v = s[mf][r] * scale;
        if (diag && (kvb + mf * 16 + rgrp * 4 + r > qi)) v = -1e30f;
        sv[mf][r] = v;
      }
    float tm = sv[0][0];
#pragma unroll
    for (int mf = 0; mf < 4; mf++)
#pragma unroll
      for (int r = 0; r < 4; r++) tm = fmaxf(tm, sv[mf][r]);
    tm = fmaxf(tm, __shfl_xor(tm, 16));
    tm = fmaxf(tm, __shfl_xor(tm, 32));
    const float mnew = fmaxf(m_run, tm);
    float p[4][4];
    float rs = 0.f;
#pragma unroll
    for (int mf = 0; mf < 4; mf++)
#pragma unroll
      for (int r = 0; r < 4; r++) { p[mf][r] = __expf(sv[mf][r] - mnew); rs += p[mf][r]; }
    rs += __shfl_xor(rs, 16);
    rs += __shfl_xor(rs, 32);
    const float alpha = __expf(m_run - mnew);
    l_run = l_run * alpha + rs;
    m_run = mnew;
#pragma unroll
    for (int mb = 0; mb < 8; mb++)
#pragma unroll
      for (int r = 0; r < 4; r++) o[mb][r] *= alpha;

#pragma unroll
    for (int mf = 0; mf < 4; mf++)
#pragma unroll
      for (int rr = 0; rr < 2; rr++) {
        unsigned int pp = (unsigned int)f2bf(p[mf][2 * rr]) |
                          ((unsigned int)f2bf(p[mf][2 * rr + 1]) << 16);
        *(unsigned int*)((char*)&Plds[wid][0] +
                         (cbase * 128 + ((mf * 32 + rgrp * 8 + rr * 4) ^ cx))) = pp;
      }
    bfx8 pf[2];
#pragma unroll
    for (int k2 = 0; k2 < 2; k2++)
      pf[k2] = *(const bfx8*)((const char*)&Plds[wid][0] +
                              (cbase * 128 + ((k2 * 64 + rgrp * 16) ^ cx)));

#pragma unroll
    for (int mb = 0; mb < 8; mb++)
#pragma unroll
      for (int k2 = 0; k2 < 2; k2++) {
        bfx8 vf = *(const bfx8*)(Vs_ + (((mb * 16 + cbase) * 128 + ((k2 * 64 + rgrp * 16) ^ cx)) >> 1));
        o[mb] = __builtin_amdgcn_mfma_f32_16x16x32_bf16(vf, pf[k2], o[mb], 0, 0, 0);
      }
    __syncthreads();
  }
#undef STAGE_T

  const float rinv = 1.0f / l_run;
  unsigned short* aop = ao + ((size_t)(b * SS + qi)) * DM + h * DH + rgrp * 4;
#pragma unroll
  for (int mb = 0; mb < 8; mb++) {
    ushort4 v;
    v.x = f2bf(o[mb][0] * rinv); v.y = f2bf(o[mb][1] * rinv);
    v.z = f2bf(o[mb][2] * rinv); v.w = f2bf(o[mb][3] * rinv);
    *(ushort4*)(aop + mb * 16) = v;
  }
}

extern "C" void kernel_launch(void* const* d_in, const int* in_sizes, int n_in,
                              void* d_out, int out_size, void* d_ws, size_t ws_size,
                              hipStream_t stream) {
  (void)in_sizes; (void)n_in; (void)out_size; (void)ws_size;
  const float* x     = (const float*)d_in[0];
  const float* w_in  = (const float*)d_in[1];
  const float* w_out = (const float*)d_in[2];
  float* out = (float*)d_out;

  char* ws = (char*)d_ws;
  unsigned short* Xb  = (unsigned short*)(ws);                     // 16 MB  [4096][2048]
  unsigned short* Wit = (unsigned short*)(ws + (16ull << 20));     // 24 MB  [6144][2048]
  unsigned short* Wot = (unsigned short*)(ws + (40ull << 20));     //  8 MB  [2048][2048]
  unsigned short* Qg  = (unsigned short*)(ws + (48ull << 20));     // 16 MB  [b][h][s][d]
  unsigned short* Kg  = (unsigned short*)(ws + (64ull << 20));     // 16 MB  [b][h][s][d]
  unsigned short* Vg  = (unsigned short*)(ws + (80ull << 20));     // 16 MB  [b][h][d][s]
  unsigned short* AO  = (unsigned short*)(ws + (96ull << 20));     // 16 MB  [4096][2048]

  f32_to_bf16_k<<<MTOT * DM / 4 / 256, 256, 0, stream>>>(x, Xb, MTOT * DM / 4);
  transpose_f32_bf16_k<<<dim3(NQKV / 32, DM / 32), 256, 0, stream>>>(w_in, Wit, DM, NQKV);
  transpose_f32_bf16_k<<<dim3(DM / 32, DM / 32), 256, 0, stream>>>(w_out, Wot, DM, DM);
  // QKV projection: 256x192 tiles -> grid 16m x 32n = 512 blocks (exactly 2 rounds)
  gemm256_qkv_k<<<512, 512, 0, stream>>>(Xb, Wit, Qg, Kg, Vg, DM);
  attn_fwd_k<<<1024, 256, 0, stream>>>(Qg, Kg, Vg, AO);
  gemm_out_k<<<dim3(DM / 128, MTOT / 128), 256, 0, stream>>>(AO, Wot, out, DM, DM);
}

// Round 15
// 235.215 us; speedup vs baseline: 1.5364x; 1.0790x over previous
//
#include <hip/hip_runtime.h>

// Problem constants
#define HD    16
#define DH    128
#define BB    2
#define SS    2048
#define DM    2048
#define NQKV  6144   // 3*HD*DH
#define MTOT  4096   // BB*SS

typedef short   bfx8  __attribute__((ext_vector_type(8)));   // 8 bf16 (4 VGPRs)
typedef float   f32x4 __attribute__((ext_vector_type(4)));

__device__ __forceinline__ unsigned short f2bf(float f) {
  union { float f; unsigned int u; } c; c.f = f;
  unsigned int u = c.u + 0x7FFFu + ((c.u >> 16) & 1u);
  return (unsigned short)(u >> 16);
}

__device__ __forceinline__ void gload_lds16(const unsigned short* g, unsigned short* l) {
  __builtin_amdgcn_global_load_lds(
      (const __attribute__((address_space(1))) unsigned int*)g,
      (__attribute__((address_space(3))) unsigned int*)l, 16, 0, 0);
}

// raw barrier fenced against compiler reordering (no vmcnt/lgkmcnt drain)
#define BARS() do { __builtin_amdgcn_sched_barrier(0); __builtin_amdgcn_s_barrier(); \
                    __builtin_amdgcn_sched_barrier(0); } while (0)
#define VMCNT7() do { asm volatile("s_waitcnt vmcnt(7)" ::: "memory"); \
                      __builtin_amdgcn_sched_barrier(0); } while (0)
#define VMCNT6() do { asm volatile("s_waitcnt vmcnt(6)" ::: "memory"); \
                      __builtin_amdgcn_sched_barrier(0); } while (0)

// ---------------- f32 -> bf16 cast ----------------
__global__ __launch_bounds__(256) void f32_to_bf16_k(const float* __restrict__ in,
                                                     unsigned short* __restrict__ out, int n4) {
  int i = (blockIdx.x * 256 + threadIdx.x);
  if (i >= n4) return;
  const float4 v = *(const float4*)(in + (size_t)i * 4);
  ushort4 o;
  o.x = f2bf(v.x); o.y = f2bf(v.y); o.z = f2bf(v.z); o.w = f2bf(v.w);
  *(ushort4*)(out + (size_t)i * 4) = o;
}

// ---------------- f32 [R][C] -> bf16 [C][R] transpose ----------------
__global__ __launch_bounds__(256) void transpose_f32_bf16_k(const float* __restrict__ in,
                                                            unsigned short* __restrict__ out,
                                                            int R, int C) {
  __shared__ float t[32][33];
  const int c0 = blockIdx.x * 32, r0 = blockIdx.y * 32;
  const int tx = threadIdx.x & 31, ty = threadIdx.x >> 5;  // 32 x 8
#pragma unroll
  for (int i = 0; i < 4; i++) {
    int r = r0 + ty + i * 8;
    t[ty + i * 8][tx] = in[(size_t)r * C + c0 + tx];
  }
  __syncthreads();
#pragma unroll
  for (int i = 0; i < 4; i++) {
    int c = c0 + ty + i * 8;
    out[(size_t)c * R + r0 + tx] = f2bf(t[tx][ty + i * 8]);
  }
}

// ---------------- 256x192 bf16 GEMM for QKV (round-14, kept) ----------------
__global__ __launch_bounds__(512, 2) void gemm256_qkv_k(const unsigned short* __restrict__ A,
                                                        const unsigned short* __restrict__ Bt,
                                                        unsigned short* __restrict__ Qg,
                                                        unsigned short* __restrict__ Kg,
                                                        unsigned short* __restrict__ Vg,
                                                        int K) {
  __shared__ __align__(16) unsigned short Asb[2][256 * 64];  // 64 KB
  __shared__ __align__(16) unsigned short Bsb[2][192 * 64];  // 48 KB
  const int tid = threadIdx.x;
  const int lane = tid & 63, wid = tid >> 6;
  const int wr = wid >> 2, wc = wid & 3;            // 2 x 4 wave grid
  const int cbase = lane & 15, rgrp = lane >> 4;
  const int bid = (int)blockIdx.x;
  const int id = (bid & 7) * 64 + (bid >> 3);       // XCD-bijective (512 = 8*64)
  const int nb = id >> 4, mb = id & 15;
  const size_t m0 = (size_t)mb * 256, n0 = (size_t)nb * 192;
  const int nkt = K >> 6;                           // 32 K-tiles (even)

#define STAGE_A64(u_, g_) do {                                                          \
    const int uc_ = ((u_) < nkt ? (u_) : (nkt - 1));                                    \
    const int r_ = tid >> 3, s_ = tid & 7;                                              \
    gload_lds16(A + (m0 + (g_) * 64 + r_) * (size_t)K + uc_ * 64 +                      \
                    (((s_ * 16) ^ ((r_ & 7) << 4)) >> 1),                               \
                &Asb[(u_) & 1][(g_) * 4096] + tid * 8); } while (0)
#define STAGE_B64(u_, g_) do {                                                          \
    const int uc_ = ((u_) < nkt ? (u_) : (nkt - 1));                                    \
    const int r_ = tid >> 3, s_ = tid & 7;                                              \
    gload_lds16(Bt + (n0 + (g_) * 64 + r_) * (size_t)K + uc_ * 64 +                     \
                    (((s_ * 16) ^ ((r_ & 7) << 4)) >> 1),                               \
                &Bsb[(u_) & 1][(g_) * 4096] + tid * 8); } while (0)

  const int axor = (cbase & 7) << 4;
  int a_off[2], b_off[2];
#pragma unroll
  for (int ks = 0; ks < 2; ks++) {
    a_off[ks] = ((wr * 128 + cbase) * 128 + ((ks * 64 + rgrp * 16) ^ axor)) >> 1;
    b_off[ks] = ((wc * 48 + cbase) * 128 + ((ks * 64 + rgrp * 16) ^ axor)) >> 1;
  }

#define RD_A03(dst_, p_) do { _Pragma("unroll")                                          \
    for (int mf_ = 0; mf_ < 4; mf_++) { _Pragma("unroll")                                \
      for (int ks_ = 0; ks_ < 2; ks_++)                                                  \
        dst_[mf_][ks_] = *(const bfx8*)((p_) + a_off[ks_] + mf_ * 1024); } } while (0)
#define RD_A47(dst_, p_) do { _Pragma("unroll")                                          \
    for (int mf_ = 0; mf_ < 4; mf_++) { _Pragma("unroll")                                \
      for (int ks_ = 0; ks_ < 2; ks_++)                                                  \
        dst_[mf_][ks_] = *(const bfx8*)((p_) + a_off[ks_] + (mf_ + 4) * 1024); } } while (0)
#define RD_B01(dst_, p_) do { _Pragma("unroll")                                          \
    for (int nf_ = 0; nf_ < 2; nf_++) { _Pragma("unroll")                                \
      for (int ks_ = 0; ks_ < 2; ks_++)                                                  \
        dst_[nf_][ks_] = *(const bfx8*)((p_) + b_off[ks_] + nf_ * 1024); } } while (0)
#define RD_B2(dst_, p_) do { _Pragma("unroll")                                           \
    for (int ks_ = 0; ks_ < 2; ks_++)                                                    \
      dst_[0][ks_] = *(const bfx8*)((p_) + b_off[ks_] + 2 * 1024); } while (0)

#define MFMA_2N(mo_, AF_, BF_) do {                                                      \
    __builtin_amdgcn_s_setprio(1);                                                      \
    _Pragma("unroll")                                                                    \
    for (int mf_ = 0; mf_ < 4; mf_++) { _Pragma("unroll")                                \
      for (int nf_ = 0; nf_ < 2; nf_++) { _Pragma("unroll")                              \
        for (int ks_ = 0; ks_ < 2; ks_++)                                                \
          acc[mf_ + (mo_)][nf_] = __builtin_amdgcn_mfma_f32_16x16x32_bf16(               \
              AF_[mf_][ks_], BF_[nf_][ks_], acc[mf_ + (mo_)][nf_], 0, 0, 0); } }         \
    __builtin_amdgcn_s_setprio(0); } while (0)

  f32x4 acc[8][3];
  const f32x4 z = {0.f, 0.f, 0.f, 0.f};
#pragma unroll
  for (int mf = 0; mf < 8; mf++)
#pragma unroll
    for (int nf = 0; nf < 3; nf++) acc[mf][nf] = z;

  STAGE_A64(0, 0); STAGE_A64(0, 1); STAGE_A64(0, 2); STAGE_A64(0, 3);
  STAGE_B64(0, 0); STAGE_B64(0, 1); STAGE_B64(0, 2);
  STAGE_A64(1, 0); STAGE_A64(1, 1); STAGE_A64(1, 2); STAGE_A64(1, 3);
  STAGE_B64(1, 0); STAGE_B64(1, 1); STAGE_B64(1, 2);
  VMCNT7();
  BARS();
  bfx8 a03A[4][2], b01A[2][2], a03B[4][2], b01B[2][2];
  RD_A03(a03A, &Asb[0][0]);
  RD_B01(b01A, &Bsb[0][0]);

#define TILE_BODY(u_, A03c, B01c, A03n, B01n) do {                                       \
    const unsigned short* As_  = &Asb[(u_) & 1][0];                                      \
    const unsigned short* Bs_  = &Bsb[(u_) & 1][0];                                      \
    const unsigned short* Asn_ = &Asb[((u_) + 1) & 1][0];                                \
    const unsigned short* Bsn_ = &Bsb[((u_) + 1) & 1][0];                                \
    bfx8 a47[4][2], b2[1][2];                                                            \
    RD_A47(a47, As_);                                                                    \
    STAGE_A64((u_) + 2, 0); STAGE_A64((u_) + 2, 2);                                      \
    BARS();                                                                              \
    MFMA_2N(0, A03c, B01c);                                                              \
    RD_B2(b2, Bs_);                                                                      \
    STAGE_A64((u_) + 2, 1); STAGE_A64((u_) + 2, 3);                                      \
    BARS();                                                                              \
    MFMA_2N(4, a47, B01c);                                                               \
    STAGE_B64((u_) + 2, 0); STAGE_B64((u_) + 2, 1); STAGE_B64((u_) + 2, 2);              \
    VMCNT7();                                                                            \
    BARS();                                                                              \
    RD_A03(A03n, Asn_);                                                                  \
    RD_B01(B01n, Bsn_);                                                                  \
    __builtin_amdgcn_s_setprio(1);                                                      \
    _Pragma("unroll")                                                                    \
    for (int mf_ = 0; mf_ < 4; mf_++) { _Pragma("unroll")                                \
      for (int ks_ = 0; ks_ < 2; ks_++) {                                                \
        acc[mf_][2] = __builtin_amdgcn_mfma_f32_16x16x32_bf16(                           \
            A03c[mf_][ks_], b2[0][ks_], acc[mf_][2], 0, 0, 0);                           \
        acc[mf_ + 4][2] = __builtin_amdgcn_mfma_f32_16x16x32_bf16(                       \
            a47[mf_][ks_], b2[0][ks_], acc[mf_ + 4][2], 0, 0, 0);                        \
      } }                                                                                \
    __builtin_amdgcn_s_setprio(0);                                                      \
    BARS();                                                                              \
  } while (0)

#pragma unroll 1
  for (int u = 0; u < nkt; u += 2) {
    TILE_BODY(u,     a03A, b01A, a03B, b01B);
    TILE_BODY(u + 1, a03B, b01B, a03A, b01A);
  }
#undef TILE_BODY
#undef STAGE_A64
#undef STAGE_B64

#pragma unroll
  for (int mf = 0; mf < 8; mf++)
#pragma unroll
    for (int nf = 0; nf < 3; nf++) {
      const int nn = (int)n0 + wc * 48 + nf * 16;
      const int h = nn / 384, tt = (nn >> 7) % 3;
      const int d = (nn & 127) + cbase;
      const int row0 = (int)m0 + wr * 128 + mf * 16 + rgrp * 4;
      const int bb = row0 >> 11;
      const int s0 = row0 & 2047;
      if (tt == 2) {
        ushort4 v;
        v.x = f2bf(acc[mf][nf][0]); v.y = f2bf(acc[mf][nf][1]);
        v.z = f2bf(acc[mf][nf][2]); v.w = f2bf(acc[mf][nf][3]);
        *(ushort4*)(Vg + ((size_t)(bb * HD + h) * DH + d) * SS + s0) = v;
      } else {
        unsigned short* dst = (tt == 0 ? Qg : Kg);
#pragma unroll
        for (int r = 0; r < 4; r++)
          dst[((size_t)(bb * HD + h) * SS + s0 + r) * DH + d] = f2bf(acc[mf][nf][r]);
      }
    }
}

// ---------------- 256x128 bf16 GEMM for out-proj: exact-grid (256 = 1 round), 2-phase ----
// 8 waves (2M x 4N), wave tile 128x32, BK=64, double-buffered swizzled LDS (96 KB).
// 2 phases/tile, 16 MFMA each, one barrier per phase (+tile-end). Register prefetch:
//   ph2(u-1): a03(u), b01(u);  ph1(u): a47(u).
// A rows: a03 = g0(0-63)+g2(128-191), a47 = g1+g3 (wave row offset wr*128).
// Staging into dead regions: ph1: A-g0,g2(u+2); ph2: A-g1,g3 + B-g0,g1(u+2).
// vmcnt(6) once per tile retires all of tile u+1 before its register prefetch.
__global__ __launch_bounds__(512, 2) void gemm256_out_k(const unsigned short* __restrict__ A,
                                                        const unsigned short* __restrict__ Bt,
                                                        float* __restrict__ C, int K, int ldc) {
  __shared__ __align__(16) unsigned short Asb[2][256 * 64];  // 64 KB
  __shared__ __align__(16) unsigned short Bsb[2][128 * 64];  // 32 KB
  const int tid = threadIdx.x;
  const int lane = tid & 63, wid = tid >> 6;
  const int wr = wid >> 2, wc = wid & 3;            // 2 x 4 wave grid
  const int cbase = lane & 15, rgrp = lane >> 4;
  const int bid = (int)blockIdx.x;
  const int id = (bid & 7) * 32 + (bid >> 3);       // XCD-bijective (256 = 8*32)
  const int nb = id >> 4, mb = id & 15;             // XCD owns 2 n-panels (1 MB B, L2-fit)
  const size_t m0 = (size_t)mb * 256, n0 = (size_t)nb * 128;
  const int nkt = K >> 6;                           // 32 K-tiles (even)

#define STAGE_AO(u_, g_) do {                                                           \
    const int uc_ = ((u_) < nkt ? (u_) : (nkt - 1));                                    \
    const int r_ = tid >> 3, s_ = tid & 7;                                              \
    gload_lds16(A + (m0 + (g_) * 64 + r_) * (size_t)K + uc_ * 64 +                      \
                    (((s_ * 16) ^ ((r_ & 7) << 4)) >> 1),                               \
                &Asb[(u_) & 1][(g_) * 4096] + tid * 8); } while (0)
#define STAGE_BO(u_, g_) do {                                                           \
    const int uc_ = ((u_) < nkt ? (u_) : (nkt - 1));                                    \
    const int r_ = tid >> 3, s_ = tid & 7;                                              \
    gload_lds16(Bt + (n0 + (g_) * 64 + r_) * (size_t)K + uc_ * 64 +                     \
                    (((s_ * 16) ^ ((r_ & 7) << 4)) >> 1),                               \
                &Bsb[(u_) & 1][(g_) * 4096] + tid * 8); } while (0)

  const int axor = (cbase & 7) << 4;
  int a_off[2], b_off[2];
#pragma unroll
  for (int ks = 0; ks < 2; ks++) {
    a_off[ks] = ((wr * 128 + cbase) * 128 + ((ks * 64 + rgrp * 16) ^ axor)) >> 1;
    b_off[ks] = ((wc * 32 + cbase) * 128 + ((ks * 64 + rgrp * 16) ^ axor)) >> 1;
  }

#define MFMA_O(mo_, AF_, BF_) do {                                                       \
    __builtin_amdgcn_s_setprio(1);                                                      \
    _Pragma("unroll")                                                                    \
    for (int mf_ = 0; mf_ < 4; mf_++) { _Pragma("unroll")                                \
      for (int nf_ = 0; nf_ < 2; nf_++) { _Pragma("unroll")                              \
        for (int ks_ = 0; ks_ < 2; ks_++)                                                \
          acc[mf_ + (mo_)][nf_] = __builtin_amdgcn_mfma_f32_16x16x32_bf16(               \
              AF_[mf_][ks_], BF_[nf_][ks_], acc[mf_ + (mo_)][nf_], 0, 0, 0); } }         \
    __builtin_amdgcn_s_setprio(0); } while (0)

  f32x4 acc[8][2];
  const f32x4 z = {0.f, 0.f, 0.f, 0.f};
#pragma unroll
  for (int mf = 0; mf < 8; mf++)
#pragma unroll
    for (int nf = 0; nf < 2; nf++) acc[mf][nf] = z;

  // prologue: stage tiles 0,1 fully (12 loads); vmcnt(6) -> tile 0 landed
  STAGE_AO(0, 0); STAGE_AO(0, 1); STAGE_AO(0, 2); STAGE_AO(0, 3);
  STAGE_BO(0, 0); STAGE_BO(0, 1);
  STAGE_AO(1, 0); STAGE_AO(1, 1); STAGE_AO(1, 2); STAGE_AO(1, 3);
  STAGE_BO(1, 0); STAGE_BO(1, 1);
  VMCNT6();
  BARS();
  bfx8 a03A[4][2], b01A[2][2], a03B[4][2], b01B[2][2];
  RD_A03(a03A, &Asb[0][0]);
  RD_B01(b01A, &Bsb[0][0]);

#define TILE_BODY_O(u_, A03c, B01c, A03n, B01n) do {                                     \
    const unsigned short* As_  = &Asb[(u_) & 1][0];                                      \
    const unsigned short* Bs_  = &Bsb[(u_) & 1][0];                                      \
    const unsigned short* Asn_ = &Asb[((u_) + 1) & 1][0];                                \
    const unsigned short* Bsn_ = &Bsb[((u_) + 1) & 1][0];                                \
    bfx8 a47[4][2];                                                                      \
    /* ph1: read a47 (g1,g3); stage A-g0,g2(u+2) (a03 read @ph2(u-1), barrier between) */\
    RD_A47(a47, As_);                                                                    \
    STAGE_AO((u_) + 2, 0); STAGE_AO((u_) + 2, 2);                                        \
    BARS();                                                                              \
    MFMA_O(0, A03c, B01c);                                                               \
    /* ph2: stage A-g1,g3 (a47 read @ph1, barrier between) + B(u+2) (read @ph2(u-1)); */ \
    /* vmcnt(6) -> tile u+1 resident; prefetch next a03/b01; MFMA a47 x b01 */           \
    STAGE_AO((u_) + 2, 1); STAGE_AO((u_) + 2, 3);                                        \
    STAGE_BO((u_) + 2, 0); STAGE_BO((u_) + 2, 1);                                        \
    VMCNT6();                                                                            \
    BARS();                                                                              \
    RD_A03(A03n, Asn_);                                                                  \
    RD_B01(B01n, Bsn_);                                                                  \
    MFMA_O(4, a47, B01c);                                                                \
    BARS();                                                                              \
  } while (0)

#pragma unroll 1
  for (int u = 0; u < nkt; u += 2) {
    TILE_BODY_O(u,     a03A, b01A, a03B, b01B);
    TILE_BODY_O(u + 1, a03B, b01B, a03A, b01A);
  }
#undef TILE_BODY_O
#undef STAGE_AO
#undef STAGE_BO

  // epilogue: f32 C
#pragma unroll
  for (int mf = 0; mf < 8; mf++)
#pragma unroll
    for (int nf = 0; nf < 2; nf++)
#pragma unroll
      for (int r = 0; r < 4; r++) {
        size_t row = m0 + wr * 128 + mf * 16 + rgrp * 4 + r;
        size_t col = n0 + wc * 32 + nf * 16 + cbase;
        C[row * ldc + col] = acc[mf][nf][r];
      }
}

// ---------------- flash attention (bf16, swapped-operand in-register softmax) ----------------
__global__ __launch_bounds__(256) void attn_fwd_k(const unsigned short* __restrict__ Qg,
                                                  const unsigned short* __restrict__ Kg,
                                                  const unsigned short* __restrict__ Vg,
                                                  unsigned short* __restrict__ ao) {
  __shared__ __align__(16) unsigned short Klds[2][64 * 128];   // 2 x 16 KB
  __shared__ __align__(16) unsigned short Vt[2][128 * 64];     // 2 x 16 KB
  __shared__ __align__(16) unsigned short Plds[4][16 * 64];    // 8 KB per-wave P rows
  const int tid = threadIdx.x;
  const int lane = tid & 63, wid = tid >> 6;
  const int cbase = lane & 15, rgrp = lane >> 4;
  const int cx = (cbase & 7) << 4;

  const int bid = (int)blockIdx.x;
  const int bh = (bid & 7) * 4 + ((bid >> 3) & 3);
  const int qt = 31 - (bid >> 5);
  const int b = bh >> 4, h = bh & 15;
  const int qbase = qt * 64;

  const unsigned short* qp0 = Qg + (size_t)(b * HD + h) * SS * DH;
  const unsigned short* kp  = Kg + (size_t)(b * HD + h) * SS * DH;
  const unsigned short* vp  = Vg + (size_t)(b * HD + h) * DH * SS;
  const float scale = 0.08838834764831845f;
  const f32x4 z = {0.f, 0.f, 0.f, 0.f};
  const int qi = qbase + wid * 16 + cbase;

  bfx8 qf[4];
  {
    const unsigned short* qp = qp0 + (size_t)qi * DH;
#pragma unroll
    for (int ks = 0; ks < 4; ks++) qf[ks] = *(const bfx8*)(qp + ks * 32 + rgrp * 8);
  }

  float m_run = -1e30f, l_run = 0.f;
  f32x4 o[8];
#pragma unroll
  for (int mb = 0; mb < 8; mb++) o[mb] = z;

#define STAGE_T(t_, s_) do {                                                        \
    const int kvb_ = (t_) * 64;                                                     \
    _Pragma("unroll")                                                               \
    for (int i_ = 0; i_ < 4; i_++) {                                                \
      int idx_ = i_ * 256 + tid;                                                    \
      int r_ = idx_ >> 4, bo_ = (idx_ & 15) * 16;                                   \
      gload_lds16(kp + (size_t)(kvb_ + r_) * DH + ((bo_ ^ ((r_ & 7) << 4)) >> 1),   \
                  &Klds[s_][idx_ * 8]);                                             \
    }                                                                               \
    _Pragma("unroll")                                                               \
    for (int i_ = 0; i_ < 4; i_++) {                                                \
      int idx_ = i_ * 256 + tid;                                                    \
      int d_ = idx_ >> 3, bo_ = (idx_ & 7) * 16;                                    \
      gload_lds16(vp + (size_t)d_ * SS + kvb_ + ((bo_ ^ ((d_ & 7) << 4)) >> 1),     \
                  &Vt[s_][idx_ * 8]);                                               \
    } } while (0)

  const int ntiles = qt + 1;
  STAGE_T(0, 0);
  __syncthreads();

  for (int t = 0; t < ntiles; ++t) {
    const int sel = t & 1;
    if (t + 1 < ntiles) STAGE_T(t + 1, sel ^ 1);
    const unsigned short* Ks_ = &Klds[sel][0];
    const unsigned short* Vs_ = &Vt[sel][0];
    const int kvb = t * 64;

    f32x4 s[4];
#pragma unroll
    for (int mf = 0; mf < 4; mf++) s[mf] = z;
#pragma unroll
    for (int mf = 0; mf < 4; mf++)
#pragma unroll
      for (int ks = 0; ks < 4; ks++) {
        bfx8 kf = *(const bfx8*)(Ks_ + (((mf * 16 + cbase) * 256 + ((ks * 64 + rgrp * 16) ^ cx)) >> 1));
        s[mf] = __builtin_amdgcn_mfma_f32_16x16x32_bf16(kf, qf[ks], s[mf], 0, 0, 0);
      }

    float sv[4][4];
    const bool diag = (t == ntiles - 1);
#pragma unroll
    for (int mf = 0; mf < 4; mf++)
#pragma unroll
      for (int r = 0; r < 4; r++) {
        float v = s[mf][r] * scale;
        if (diag && (kvb + mf * 16 + rgrp * 4 + r > qi)) v = -1e30f;
        sv[mf][r] = v;
      }
    float tm = sv[0][0];
#pragma unroll
    for (int mf = 0; mf < 4; mf++)
#pragma unroll
      for (int r = 0; r < 4; r++) tm = fmaxf(tm, sv[mf][r]);
    tm = fmaxf(tm, __shfl_xor(tm, 16));
    tm = fmaxf(tm, __shfl_xor(tm, 32));
    const float mnew = fmaxf(m_run, tm);
    float p[4][4];
    float rs = 0.f;
#pragma unroll
    for (int mf = 0; mf < 4; mf++)
#pragma unroll
      for (int r = 0; r < 4; r++) { p[mf][r] = __expf(sv[mf][r] - mnew); rs += p[mf][r]; }
    rs += __shfl_xor(rs, 16);
    rs += __shfl_xor(rs, 32);
    const float alpha = __expf(m_run - mnew);
    l_run = l_run * alpha + rs;
    m_run = mnew;
#pragma unroll
    for (int mb = 0; mb < 8; mb++)
#pragma unroll
      for (int r = 0; r < 4; r++) o[mb][r] *= alpha;

#pragma unroll
    for (int mf = 0; mf < 4; mf++)
#pragma unroll
      for (int rr = 0; rr < 2; rr++) {
        unsigned int pp = (unsigned int)f2bf(p[mf][2 * rr]) |
                          ((unsigned int)f2bf(p[mf][2 * rr + 1]) << 16);
        *(unsigned int*)((char*)&Plds[wid][0] +
                         (cbase * 128 + ((mf * 32 + rgrp * 8 + rr * 4) ^ cx))) = pp;
      }
    bfx8 pf[2];
#pragma unroll
    for (int k2 = 0; k2 < 2; k2++)
      pf[k2] = *(const bfx8*)((const char*)&Plds[wid][0] +
                              (cbase * 128 + ((k2 * 64 + rgrp * 16) ^ cx)));

#pragma unroll
    for (int mb = 0; mb < 8; mb++)
#pragma unroll
      for (int k2 = 0; k2 < 2; k2++) {
        bfx8 vf = *(const bfx8*)(Vs_ + (((mb * 16 + cbase) * 128 + ((k2 * 64 + rgrp * 16) ^ cx)) >> 1));
        o[mb] = __builtin_amdgcn_mfma_f32_16x16x32_bf16(vf, pf[k2], o[mb], 0, 0, 0);
      }
    __syncthreads();
  }
#undef STAGE_T

  const float rinv = 1.0f / l_run;
  unsigned short* aop = ao + ((size_t)(b * SS + qi)) * DM + h * DH + rgrp * 4;
#pragma unroll
  for (int mb = 0; mb < 8; mb++) {
    ushort4 v;
    v.x = f2bf(o[mb][0] * rinv); v.y = f2bf(o[mb][1] * rinv);
    v.z = f2bf(o[mb][2] * rinv); v.w = f2bf(o[mb][3] * rinv);
    *(ushort4*)(aop + mb * 16) = v;
  }
}

extern "C" void kernel_launch(void* const* d_in, const int* in_sizes, int n_in,
                              void* d_out, int out_size, void* d_ws, size_t ws_size,
                              hipStream_t stream) {
  (void)in_sizes; (void)n_in; (void)out_size; (void)ws_size;
  const float* x     = (const float*)d_in[0];
  const float* w_in  = (const float*)d_in[1];
  const float* w_out = (const float*)d_in[2];
  float* out = (float*)d_out;

  char* ws = (char*)d_ws;
  unsigned short* Xb  = (unsigned short*)(ws);                     // 16 MB  [4096][2048]
  unsigned short* Wit = (unsigned short*)(ws + (16ull << 20));     // 24 MB  [6144][2048]
  unsigned short* Wot = (unsigned short*)(ws + (40ull << 20));     //  8 MB  [2048][2048]
  unsigned short* Qg  = (unsigned short*)(ws + (48ull << 20));     // 16 MB  [b][h][s][d]
  unsigned short* Kg  = (unsigned short*)(ws + (64ull << 20));     // 16 MB  [b][h][s][d]
  unsigned short* Vg  = (unsigned short*)(ws + (80ull << 20));     // 16 MB  [b][h][d][s]
  unsigned short* AO  = (unsigned short*)(ws + (96ull << 20));     // 16 MB  [4096][2048]

  f32_to_bf16_k<<<MTOT * DM / 4 / 256, 256, 0, stream>>>(x, Xb, MTOT * DM / 4);
  transpose_f32_bf16_k<<<dim3(NQKV / 32, DM / 32), 256, 0, stream>>>(w_in, Wit, DM, NQKV);
  transpose_f32_bf16_k<<<dim3(DM / 32, DM / 32), 256, 0, stream>>>(w_out, Wot, DM, DM);
  // QKV projection: 256x192 tiles -> grid 512 (exactly 2 rounds)
  gemm256_qkv_k<<<512, 512, 0, stream>>>(Xb, Wit, Qg, Kg, Vg, DM);
  attn_fwd_k<<<1024, 256, 0, stream>>>(Qg, Kg, Vg, AO);
  // out = AO @ Wot^T (f32): 256x128 tiles -> grid 256 (exactly 1 round)
  gemm256_out_k<<<256, 512, 0, stream>>>(AO, Wot, out, DM, DM);
}